// Round 7
// baseline (426.526 us; speedup 1.0000x reference)
//
#include <hip/hip_runtime.h>
#include <math.h>

// Problem constants (B=1)
#define S_LEN   4096
#define D_MODEL 768
#define N_HEAD  12
#define H_DIM   64
#define NELEM   (S_LEN * D_MODEL)    // 3,145,728
#define WELEM   (D_MODEL * D_MODEL)  // 589,824

typedef unsigned short ushort;
typedef __attribute__((ext_vector_type(8))) short short8;
typedef __attribute__((ext_vector_type(4))) float f32x4;

__device__ __forceinline__ ushort f2bh(float f) {
  unsigned u = __float_as_uint(f);
  u += 0x7fffu + ((u >> 16) & 1u);  // round-to-nearest-even
  return (ushort)(u >> 16);
}
__device__ __forceinline__ float bh2f(ushort h) {
  return __uint_as_float(((unsigned)h) << 16);
}

// XOR swizzle for 128B LDS rows: spreads 16B slots across banks.
#define SWZ(row, colByte) ((((row) * 128) + (colByte)) ^ (((row) & 7) << 4))

// ============================================================================
// convert_x: fp32 -> bf16 hi/lo planes (element-wise, 4/thread)
// ============================================================================
__global__ __launch_bounds__(256)
void convert_x(const float* __restrict__ x, ushort* __restrict__ xh,
               ushort* __restrict__ xl) {
  size_t i = ((size_t)blockIdx.x * 256 + threadIdx.x) * 4;
  float4 v = *reinterpret_cast<const float4*>(&x[i]);
  ushort4 hv, lv;
  hv.x = f2bh(v.x); lv.x = f2bh(v.x - bh2f(hv.x));
  hv.y = f2bh(v.y); lv.y = f2bh(v.y - bh2f(hv.y));
  hv.z = f2bh(v.z); lv.z = f2bh(v.z - bh2f(hv.z));
  hv.w = f2bh(v.w); lv.w = f2bh(v.w - bh2f(hv.w));
  *reinterpret_cast<ushort4*>(&xh[i]) = hv;
  *reinterpret_cast<ushort4*>(&xl[i]) = lv;
}

// convert_w: 4 weight matrices -> hi/lo planes (plane z: 0=q,1=k,2=v,3=o)
__global__ __launch_bounds__(256)
void convert_w(const float* __restrict__ wq, const float* __restrict__ wk,
               const float* __restrict__ wv, const float* __restrict__ wo,
               ushort* __restrict__ WH, ushort* __restrict__ WL) {
  int z = blockIdx.z;
  const float* src = (z == 0) ? wq : (z == 1) ? wk : (z == 2) ? wv : wo;
  ushort* oh = WH + (size_t)z * WELEM;
  ushort* ol = WL + (size_t)z * WELEM;
  size_t i = ((size_t)blockIdx.x * 256 + threadIdx.x) * 4;
  float4 v = *reinterpret_cast<const float4*>(&src[i]);
  ushort4 hv, lv;
  hv.x = f2bh(v.x); lv.x = f2bh(v.x - bh2f(hv.x));
  hv.y = f2bh(v.y); lv.y = f2bh(v.y - bh2f(hv.y));
  hv.z = f2bh(v.z); lv.z = f2bh(v.z - bh2f(hv.z));
  hv.w = f2bh(v.w); lv.w = f2bh(v.w - bh2f(hv.w));
  *reinterpret_cast<ushort4*>(&oh[i]) = hv;
  *reinterpret_cast<ushort4*>(&ol[i]) = lv;
}

// ============================================================================
// bf16x3 MFMA GEMM core: C[128x64] += A(hi+lo) * W(hi+lo)^T
// 256 thr = 4 waves (2x2); wave = 64x32 sub-tile = 4x2 16x16 frags.
// BK=64, swizzled LDS. T14 prefetch in NAMED registers (arrays/lambdas go to
// scratch -- R3 lesson: 500MB HBM writes).
// ============================================================================
__device__ __forceinline__ void gemm_bf3_core(
    const ushort* __restrict__ Ah, const ushort* __restrict__ Al,
    const ushort* __restrict__ Wh, const ushort* __restrict__ Wl,
    int rowbase, int colbase, f32x4 (&acc)[4][2]) {
  __shared__ __align__(16) ushort AhS[128 * 64];
  __shared__ __align__(16) ushort AlS[128 * 64];
  __shared__ __align__(16) ushort WhS[64 * 64];
  __shared__ __align__(16) ushort WlS[64 * 64];
  char* AhB = (char*)AhS; char* AlB = (char*)AlS;
  char* WhB = (char*)WhS; char* WlB = (char*)WlS;

  const int tid  = threadIdx.x;
  const int lane = tid & 63;
  const int w    = tid >> 6;
  const int wm   = w >> 1;
  const int wn   = w & 1;
  const int lr   = lane & 15;
  const int lk   = lane >> 4;

  const int r0 = tid >> 3;          // 0..31
  const int cb = (tid & 7) * 16;    // byte col in LDS row
  const int ce = (tid & 7) * 8;     // element col
  const int sA0 = SWZ(r0, cb);
  const int sA1 = SWZ(r0 + 32, cb);
  const int sA2 = SWZ(r0 + 64, cb);
  const int sA3 = SWZ(r0 + 96, cb);

#pragma unroll
  for (int mt = 0; mt < 4; ++mt)
#pragma unroll
    for (int nt = 0; nt < 2; ++nt) acc[mt][nt] = {0.f, 0.f, 0.f, 0.f};

  // Named prefetch registers (A: 4 row-groups x hi/lo; W: 2 x hi/lo).
  float4 gA0h, gA1h, gA2h, gA3h, gA0l, gA1l, gA2l, gA3l;
  float4 gW0h, gW1h, gW0l, gW1l;

#define GEMM_ISSUE(k0_)                                                     \
  {                                                                         \
    size_t oA = (size_t)(rowbase + r0) * D_MODEL + (k0_) + ce;              \
    const size_t st = 32 * (size_t)D_MODEL;                                 \
    gA0h = *reinterpret_cast<const float4*>(Ah + oA);                       \
    gA1h = *reinterpret_cast<const float4*>(Ah + oA + st);                  \
    gA2h = *reinterpret_cast<const float4*>(Ah + oA + 2 * st);              \
    gA3h = *reinterpret_cast<const float4*>(Ah + oA + 3 * st);              \
    gA0l = *reinterpret_cast<const float4*>(Al + oA);                       \
    gA1l = *reinterpret_cast<const float4*>(Al + oA + st);                  \
    gA2l = *reinterpret_cast<const float4*>(Al + oA + 2 * st);              \
    gA3l = *reinterpret_cast<const float4*>(Al + oA + 3 * st);              \
    size_t oW = (size_t)(colbase + r0) * D_MODEL + (k0_) + ce;              \
    gW0h = *reinterpret_cast<const float4*>(Wh + oW);                       \
    gW1h = *reinterpret_cast<const float4*>(Wh + oW + st);                  \
    gW0l = *reinterpret_cast<const float4*>(Wl + oW);                       \
    gW1l = *reinterpret_cast<const float4*>(Wl + oW + st);                  \
  }

  GEMM_ISSUE(0);
  for (int ks = 0; ks < D_MODEL / 64; ++ks) {
    __syncthreads();  // prior compute done reading LDS
    *reinterpret_cast<float4*>(AhB + sA0) = gA0h;
    *reinterpret_cast<float4*>(AhB + sA1) = gA1h;
    *reinterpret_cast<float4*>(AhB + sA2) = gA2h;
    *reinterpret_cast<float4*>(AhB + sA3) = gA3h;
    *reinterpret_cast<float4*>(AlB + sA0) = gA0l;
    *reinterpret_cast<float4*>(AlB + sA1) = gA1l;
    *reinterpret_cast<float4*>(AlB + sA2) = gA2l;
    *reinterpret_cast<float4*>(AlB + sA3) = gA3l;
    *reinterpret_cast<float4*>(WhB + sA0) = gW0h;
    *reinterpret_cast<float4*>(WhB + sA1) = gW1h;
    *reinterpret_cast<float4*>(WlB + sA0) = gW0l;
    *reinterpret_cast<float4*>(WlB + sA1) = gW1l;
    __syncthreads();
    if (ks < D_MODEL / 64 - 1) GEMM_ISSUE((ks + 1) * 64);  // hide under MFMA

#pragma unroll
    for (int kc = 0; kc < 2; ++kc) {
      short8 ah[4], al[4], bh[2], bl[2];
#pragma unroll
      for (int mt = 0; mt < 4; ++mt) {
        int o = SWZ(wm * 64 + mt * 16 + lr, kc * 64 + lk * 16);
        ah[mt] = *reinterpret_cast<const short8*>(AhB + o);
        al[mt] = *reinterpret_cast<const short8*>(AlB + o);
      }
#pragma unroll
      for (int nt = 0; nt < 2; ++nt) {
        int o = SWZ(wn * 32 + nt * 16 + lr, kc * 64 + lk * 16);
        bh[nt] = *reinterpret_cast<const short8*>(WhB + o);
        bl[nt] = *reinterpret_cast<const short8*>(WlB + o);
      }
#pragma unroll
      for (int mt = 0; mt < 4; ++mt)
#pragma unroll
        for (int nt = 0; nt < 2; ++nt) {
          acc[mt][nt] = __builtin_amdgcn_mfma_f32_16x16x32_bf16(
              ah[mt], bh[nt], acc[mt][nt], 0, 0, 0);
          acc[mt][nt] = __builtin_amdgcn_mfma_f32_16x16x32_bf16(
              al[mt], bh[nt], acc[mt][nt], 0, 0, 0);
          acc[mt][nt] = __builtin_amdgcn_mfma_f32_16x16x32_bf16(
              ah[mt], bl[nt], acc[mt][nt], 0, 0, 0);
        }
    }
  }
#undef GEMM_ISSUE
}

// QKV projections: grid (12, 32, 3); z: 0=Q(scale (1/8)/ln2), 1=K, 2=V.
// Q pre-scaled so softmax runs in exp2 domain (native v_exp_f32).
__global__ __launch_bounds__(256)
void gemm_qkv_bf3(const ushort* __restrict__ xh, const ushort* __restrict__ xl,
                  const ushort* __restrict__ WH, const ushort* __restrict__ WL,
                  ushort* __restrict__ QKV) {
  const int z = blockIdx.z;
  const ushort* Wh = WH + (size_t)z * WELEM;
  const ushort* Wl = WL + (size_t)z * WELEM;
  ushort* oh = QKV + (size_t)z * (2 * NELEM);
  ushort* ol = oh + NELEM;
  const float scale = (z == 0) ? 0.125f * 1.44269504089f : 1.0f;
  const int rowbase = blockIdx.y * 128;
  const int colbase = blockIdx.x * 64;

  f32x4 acc[4][2];
  gemm_bf3_core(xh, xl, Wh, Wl, rowbase, colbase, acc);

  const int lane = threadIdx.x & 63, w = threadIdx.x >> 6;
  const int wm = w >> 1, wn = w & 1, lr = lane & 15, lk = lane >> 4;
#pragma unroll
  for (int mt = 0; mt < 4; ++mt)
#pragma unroll
    for (int nt = 0; nt < 2; ++nt)
#pragma unroll
      for (int j = 0; j < 4; ++j) {
        int rg = rowbase + wm * 64 + mt * 16 + lk * 4 + j;
        int cg = colbase + wn * 32 + nt * 16 + lr;
        float v = acc[mt][nt][j] * scale;
        ushort hh = f2bh(v);
        oh[(size_t)rg * D_MODEL + cg] = hh;
        ol[(size_t)rg * D_MODEL + cg] = f2bh(v - bh2f(hh));
      }
}

// Output projection: fp32 out + bias.
__global__ __launch_bounds__(256)
void gemm_out_bf3(const ushort* __restrict__ ch, const ushort* __restrict__ cl,
                  const ushort* __restrict__ woh, const ushort* __restrict__ wol,
                  const float* __restrict__ bo, float* __restrict__ out) {
  const int rowbase = blockIdx.y * 128;
  const int colbase = blockIdx.x * 64;
  f32x4 acc[4][2];
  gemm_bf3_core(ch, cl, woh, wol, rowbase, colbase, acc);

  const int lane = threadIdx.x & 63, w = threadIdx.x >> 6;
  const int wm = w >> 1, wn = w & 1, lr = lane & 15, lk = lane >> 4;
#pragma unroll
  for (int nt = 0; nt < 2; ++nt) {
    int cg = colbase + wn * 32 + nt * 16 + lr;
    float bb = bo[cg];
#pragma unroll
    for (int mt = 0; mt < 4; ++mt)
#pragma unroll
      for (int j = 0; j < 4; ++j) {
        int rg = rowbase + wm * 64 + mt * 16 + lk * 4 + j;
        out[(size_t)rg * D_MODEL + cg] = acc[mt][nt][j] + bb;
      }
  }
}

// ============================================================================
// V transpose: row-major hi/lo planes -> [h][d][s] hi/lo planes.
// ============================================================================
__global__ __launch_bounds__(256)
void convert_vt(const ushort* __restrict__ Vrh, const ushort* __restrict__ Vrl,
                ushort* __restrict__ Vth, ushort* __restrict__ Vtl) {
  __shared__ ushort th[64][68];
  __shared__ ushort tl[64][68];
  const int tid = threadIdx.x;
  const int s0  = blockIdx.x * 64;
  const int h   = blockIdx.y;
#pragma unroll
  for (int it = 0; it < 4; ++it) {
    int id = tid + it * 256;
    int s  = id >> 4;
    int c4 = (id & 15) * 4;
    size_t g = (size_t)(s0 + s) * D_MODEL + h * H_DIM + c4;
    ushort4 vh = *reinterpret_cast<const ushort4*>(&Vrh[g]);
    ushort4 vl = *reinterpret_cast<const ushort4*>(&Vrl[g]);
    th[c4 + 0][s] = vh.x; th[c4 + 1][s] = vh.y;
    th[c4 + 2][s] = vh.z; th[c4 + 3][s] = vh.w;
    tl[c4 + 0][s] = vl.x; tl[c4 + 1][s] = vl.y;
    tl[c4 + 2][s] = vl.z; tl[c4 + 3][s] = vl.w;
  }
  __syncthreads();
#pragma unroll
  for (int it = 0; it < 4; ++it) {
    int id = tid + it * 256;
    int d  = id >> 4;
    int s4 = (id & 15) * 4;
    ushort4 oh, ol;
    oh.x = th[d][s4 + 0]; oh.y = th[d][s4 + 1];
    oh.z = th[d][s4 + 2]; oh.w = th[d][s4 + 3];
    ol.x = tl[d][s4 + 0]; ol.y = tl[d][s4 + 1];
    ol.z = tl[d][s4 + 2]; ol.w = tl[d][s4 + 3];
    size_t o = (size_t)(h * H_DIM + d) * S_LEN + s0 + s4;
    *reinterpret_cast<ushort4*>(&Vth[o]) = oh;
    *reinterpret_cast<ushort4*>(&Vtl[o]) = ol;
  }
}

// ============================================================================
// Flash attention fwd (causal), bf16x3 MFMA (QK^T) + bf16x2 (PV, P-hi only),
// fp32 online softmax in exp2 domain, FINE SPLIT-K (chunks of <=16 K-tiles).
// Grid (160, 12):
//   bx 0..127:  qb = 32 + (bx>>2), c = bx&3, nch = qb>=48 ? 4 : 3.
//               c >= nch -> early exit. kt [16c, min(16c+16, qb+1)).
//               -> partial slot h*112 + (qb<48 ? (qb-32)*3+c : 48+(qb-48)*4+c)
//   bx 128..159: qb = 159-bx (31..0, heavy first), full range, direct CTX.
// 112 partial slots/head; 1728 valid blocks -> dispatcher refill + short poles.
// LDS = 40960 B -> 4 blocks/CU. T13-exact skip of alpha-rescale.
// ============================================================================
__global__ __launch_bounds__(256)
void attn_mfma(const ushort* __restrict__ Qh_g, const ushort* __restrict__ Ql_g,
               const ushort* __restrict__ Kh_g, const ushort* __restrict__ Kl_g,
               const ushort* __restrict__ Vh_g, const ushort* __restrict__ Vl_g,
               ushort* __restrict__ CTXh, ushort* __restrict__ CTXl,
               float* __restrict__ O_part, float* __restrict__ m_part,
               float* __restrict__ l_part) {
  const int bx = blockIdx.x;
  const int h  = blockIdx.y;
  int qb, kt0, kt1, slot = 0, partial;
  if (bx < 128) {
    qb = 32 + (bx >> 2);
    int c   = bx & 3;
    int nch = (qb >= 48) ? 4 : 3;
    if (c >= nch) return;  // padding block
    kt0 = c * 16;
    kt1 = min(kt0 + 16, qb + 1);
    partial = 1;
    int sh = (qb < 48) ? (qb - 32) * 3 + c : 48 + (qb - 48) * 4 + c;
    slot = h * 112 + sh;
  } else {
    qb = 159 - bx;  // 31..0, heaviest first
    kt0 = 0; kt1 = qb + 1; partial = 0;
  }

  __shared__ __align__(16) ushort Kh_s[64 * 64];
  __shared__ __align__(16) ushort Kl_s[64 * 64];
  __shared__ __align__(16) ushort Vh_s[64 * 64];
  __shared__ __align__(16) ushort Vl_s[64 * 64];
  __shared__ __align__(16) ushort P_s[4][16 * 64];  // per-wave P hi, swizzled

  char* KhB = (char*)Kh_s;
  char* KlB = (char*)Kl_s;
  char* VhB = (char*)Vh_s;
  char* VlB = (char*)Vl_s;

  const int tid  = threadIdx.x;
  const int lane = tid & 63;
  const int w    = tid >> 6;
  const int lr   = lane & 15;
  const int lk   = lane >> 4;
  const float NEG = -1e30f;

  const int r0 = tid >> 3;          // 0..31
  const int cb = (tid & 7) * 16;
  const int ce = (tid & 7) * 8;
  const int swA = SWZ(r0, cb);
  const int swB = SWZ(r0 + 32, cb);

  // ---- Prologue: stage Q tile through K buffers, hoist A-frags to regs ----
  {
    size_t g0 = (size_t)(qb * 64 + r0) * D_MODEL + h * H_DIM + ce;
    size_t g1 = g0 + 32 * (size_t)D_MODEL;
    *reinterpret_cast<float4*>(KhB + swA) =
        *reinterpret_cast<const float4*>(Qh_g + g0);
    *reinterpret_cast<float4*>(KhB + swB) =
        *reinterpret_cast<const float4*>(Qh_g + g1);
    *reinterpret_cast<float4*>(KlB + swA) =
        *reinterpret_cast<const float4*>(Ql_g + g0);
    *reinterpret_cast<float4*>(KlB + swB) =
        *reinterpret_cast<const float4*>(Ql_g + g1);
  }
  __syncthreads();
  short8 aqh[2], aql[2];
#pragma unroll
  for (int kc = 0; kc < 2; ++kc) {
    int ao = SWZ(w * 16 + lr, kc * 64 + lk * 16);
    aqh[kc] = *reinterpret_cast<const short8*>(KhB + ao);
    aql[kc] = *reinterpret_cast<const short8*>(KlB + ao);
  }

  f32x4 o[4];
  float m[4], l[4];
#pragma unroll
  for (int t = 0; t < 4; ++t) o[t] = {0.f, 0.f, 0.f, 0.f};
#pragma unroll
  for (int r = 0; r < 4; ++r) { m[r] = NEG; l[r] = 0.f; }

  // T14 prefetch: named registers only.
  float4 gkh0, gkh1, gkl0, gkl1, gvh0, gvh1, gvl0, gvl1;

#define ATTN_ISSUE(kt_)                                                     \
  {                                                                         \
    size_t gk0 = (size_t)((kt_) * 64 + r0) * D_MODEL + h * H_DIM + ce;      \
    size_t gk1 = gk0 + 32 * (size_t)D_MODEL;                                \
    size_t gv0 = (size_t)(h * H_DIM + r0) * S_LEN + (kt_) * 64 + ce;        \
    size_t gv1 = gv0 + 32 * (size_t)S_LEN;                                  \
    gkh0 = *reinterpret_cast<const float4*>(Kh_g + gk0);                    \
    gkh1 = *reinterpret_cast<const float4*>(Kh_g + gk1);                    \
    gkl0 = *reinterpret_cast<const float4*>(Kl_g + gk0);                    \
    gkl1 = *reinterpret_cast<const float4*>(Kl_g + gk1);                    \
    gvh0 = *reinterpret_cast<const float4*>(Vh_g + gv0);                    \
    gvh1 = *reinterpret_cast<const float4*>(Vh_g + gv1);                    \
    gvl0 = *reinterpret_cast<const float4*>(Vl_g + gv0);                    \
    gvl1 = *reinterpret_cast<const float4*>(Vl_g + gv1);                    \
  }

  ATTN_ISSUE(kt0);

  for (int kt = kt0; kt < kt1; ++kt) {
    __syncthreads();  // prior tile's LDS reads done (covers Q-frag reads too)
    *reinterpret_cast<float4*>(KhB + swA) = gkh0;
    *reinterpret_cast<float4*>(KhB + swB) = gkh1;
    *reinterpret_cast<float4*>(KlB + swA) = gkl0;
    *reinterpret_cast<float4*>(KlB + swB) = gkl1;
    *reinterpret_cast<float4*>(VhB + swA) = gvh0;
    *reinterpret_cast<float4*>(VhB + swB) = gvh1;
    *reinterpret_cast<float4*>(VlB + swA) = gvl0;
    *reinterpret_cast<float4*>(VlB + swB) = gvl1;
    __syncthreads();
    if (kt + 1 < kt1) ATTN_ISSUE(kt + 1);  // in flight during compute

    // ---- S' = Q K^T / (8 ln2)  (bf16x3; Q pre-scaled) ----
    f32x4 sacc[4];
#pragma unroll
    for (int t = 0; t < 4; ++t) sacc[t] = {0.f, 0.f, 0.f, 0.f};
#pragma unroll
    for (int kc = 0; kc < 2; ++kc) {
#pragma unroll
      for (int t = 0; t < 4; ++t) {
        int bo = SWZ(t * 16 + lr, kc * 64 + lk * 16);
        short8 bh = *reinterpret_cast<const short8*>(KhB + bo);
        short8 bl = *reinterpret_cast<const short8*>(KlB + bo);
        sacc[t] = __builtin_amdgcn_mfma_f32_16x16x32_bf16(aqh[kc], bh, sacc[t], 0, 0, 0);
        sacc[t] = __builtin_amdgcn_mfma_f32_16x16x32_bf16(aql[kc], bh, sacc[t], 0, 0, 0);
        sacc[t] = __builtin_amdgcn_mfma_f32_16x16x32_bf16(aqh[kc], bl, sacc[t], 0, 0, 0);
      }
    }

    // ---- causal mask on the diagonal tile ----
    if (kt == qb) {
#pragma unroll
      for (int t = 0; t < 4; ++t) {
        int colg = t * 16 + lr;
#pragma unroll
        for (int r = 0; r < 4; ++r) {
          int rowg = w * 16 + lk * 4 + r;
          if (colg > rowg) sacc[t][r] = NEG;
        }
      }
    }

    // ---- online softmax, exp2 domain; T13-exact rescale skip ----
    float pf[4][4];  // [t][r]
#pragma unroll
    for (int r = 0; r < 4; ++r) {
      float mx = fmaxf(fmaxf(sacc[0][r], sacc[1][r]),
                       fmaxf(sacc[2][r], sacc[3][r]));
      mx = fmaxf(mx, __shfl_xor(mx, 1));
      mx = fmaxf(mx, __shfl_xor(mx, 2));
      mx = fmaxf(mx, __shfl_xor(mx, 4));
      mx = fmaxf(mx, __shfl_xor(mx, 8));
      if (__any(mx > m[r])) {  // rescale only if some row's max grew (exact)
        float mnew  = fmaxf(m[r], mx);
        float alpha = exp2f(m[r] - mnew);
        m[r] = mnew;
        l[r] *= alpha;
#pragma unroll
        for (int t = 0; t < 4; ++t) o[t][r] *= alpha;
      }
      float rs = 0.f;
#pragma unroll
      for (int t = 0; t < 4; ++t) {
        float p = exp2f(sacc[t][r] - m[r]);
        pf[t][r] = p;
        rs += p;
      }
      rs += __shfl_xor(rs, 1);
      rs += __shfl_xor(rs, 2);
      rs += __shfl_xor(rs, 4);
      rs += __shfl_xor(rs, 8);
      l[r] += rs;
    }

    // ---- P(hi only) -> per-wave swizzled u16 LDS ----
    char* pwB = (char*)P_s[w];
#pragma unroll
    for (int r = 0; r < 4; ++r) {
      int prow = lk * 4 + r;
#pragma unroll
      for (int t = 0; t < 4; ++t) {
        int off = SWZ(prow, (t * 16 + lr) * 2);
        *reinterpret_cast<ushort*>(pwB + off) = f2bh(pf[t][r]);
      }
    }

    // ---- O += P V (P-hi x (Vh+Vl): 2 MFMAs per (kc,t)) ----
#pragma unroll
    for (int kc = 0; kc < 2; ++kc) {
      short8 pa = *reinterpret_cast<const short8*>(
          pwB + SWZ(lr, kc * 64 + lk * 16));
#pragma unroll
      for (int t = 0; t < 4; ++t) {
        int bo = SWZ(t * 16 + lr, kc * 64 + lk * 16);
        short8 vh = *reinterpret_cast<const short8*>(VhB + bo);
        short8 vl = *reinterpret_cast<const short8*>(VlB + bo);
        o[t] = __builtin_amdgcn_mfma_f32_16x16x32_bf16(pa, vh, o[t], 0, 0, 0);
        o[t] = __builtin_amdgcn_mfma_f32_16x16x32_bf16(pa, vl, o[t], 0, 0, 0);
      }
    }
  }
#undef ATTN_ISSUE

  if (!partial) {
    // ---- direct epilogue: normalize, store ctx as hi/lo bf16 planes ----
    float inv[4];
#pragma unroll
    for (int r = 0; r < 4; ++r) inv[r] = 1.f / l[r];
#pragma unroll
    for (int t = 0; t < 4; ++t)
#pragma unroll
      for (int r = 0; r < 4; ++r) {
        size_t idx = (size_t)(qb * 64 + w * 16 + lk * 4 + r) * D_MODEL +
                     h * H_DIM + t * 16 + lr;
        float v = o[t][r] * inv[r];
        ushort hh = f2bh(v);
        CTXh[idx] = hh;
        CTXl[idx] = f2bh(v - bh2f(hh));
      }
  } else {
    // ---- partial epilogue: unnormalized fp32 O + m + l (m in log2) ----
    float* Ob = O_part + (size_t)slot * 4096;
#pragma unroll
    for (int t = 0; t < 4; ++t)
#pragma unroll
      for (int r = 0; r < 4; ++r)
        Ob[(w * 16 + lk * 4 + r) * 64 + t * 16 + lr] = o[t][r];
    if (lr == 0) {
#pragma unroll
      for (int r = 0; r < 4; ++r) {
        int row = w * 16 + lk * 4 + r;
        m_part[slot * 64 + row] = m[r];
        l_part[slot * 64 + row] = l[r];
      }
    }
  }
}

// ============================================================================
// Combine 3-4 partials per (h, qb>=32): O = sum O_c 2^(m_c-M); ctx = O/L.
// Grid (32, 12), 256 threads; thread handles (row, 16 dims). The absent 4th
// chunk (qb<48) is read in-bounds (next head's slot) but weighted 0.
// ============================================================================
__global__ __launch_bounds__(256)
void attn_combine(const float* __restrict__ O_part,
                  const float* __restrict__ m_part,
                  const float* __restrict__ l_part,
                  ushort* __restrict__ CTXh, ushort* __restrict__ CTXl) {
  const int qb  = 32 + blockIdx.x;
  const int h   = blockIdx.y;
  const int tid = threadIdx.x;
  const int row = tid >> 2;        // 0..63
  const int d0  = (tid & 3) * 16;  // 0,16,32,48
  const int nch = (qb >= 48) ? 4 : 3;
  const int sh0 = (qb < 48) ? (qb - 32) * 3 : 48 + (qb - 48) * 4;
  const int sb  = h * 112 + sh0;
  // Guard slot for the absent 4th chunk: clamp into the valid range (weighted 0).
  const int s3  = (nch == 4) ? sb + 3 : sb;

  float m0 = m_part[(sb + 0) * 64 + row];
  float m1 = m_part[(sb + 1) * 64 + row];
  float m2 = m_part[(sb + 2) * 64 + row];
  float m3 = (nch == 4) ? m_part[s3 * 64 + row] : -1e30f;
  float l0 = l_part[(sb + 0) * 64 + row];
  float l1 = l_part[(sb + 1) * 64 + row];
  float l2 = l_part[(sb + 2) * 64 + row];
  float l3 = (nch == 4) ? l_part[s3 * 64 + row] : 0.f;
  float M  = fmaxf(fmaxf(m0, m1), fmaxf(m2, m3));
  float a0 = exp2f(m0 - M);
  float a1 = exp2f(m1 - M);
  float a2 = exp2f(m2 - M);
  float a3 = (nch == 4) ? exp2f(m3 - M) : 0.f;
  float inv = 1.0f / (l0 * a0 + l1 * a1 + l2 * a2 + l3 * a3);

  const float* p0 = O_part + (size_t)(sb + 0) * 4096 + row * 64 + d0;
  const float* p1 = O_part + (size_t)(sb + 1) * 4096 + row * 64 + d0;
  const float* p2 = O_part + (size_t)(sb + 2) * 4096 + row * 64 + d0;
  const float* p3 = O_part + (size_t)s3 * 4096 + row * 64 + d0;
  size_t ob = (size_t)(qb * 64 + row) * D_MODEL + h * H_DIM + d0;
#pragma unroll
  for (int j = 0; j < 16; j += 4) {
    float4 x0 = *reinterpret_cast<const float4*>(p0 + j);
    float4 x1 = *reinterpret_cast<const float4*>(p1 + j);
    float4 x2 = *reinterpret_cast<const float4*>(p2 + j);
    float4 x3 = *reinterpret_cast<const float4*>(p3 + j);
    float4 v;
    v.x = (x0.x * a0 + x1.x * a1 + x2.x * a2 + x3.x * a3) * inv;
    v.y = (x0.y * a0 + x1.y * a1 + x2.y * a2 + x3.y * a3) * inv;
    v.z = (x0.z * a0 + x1.z * a1 + x2.z * a2 + x3.z * a3) * inv;
    v.w = (x0.w * a0 + x1.w * a1 + x2.w * a2 + x3.w * a3) * inv;
    ushort4 hv, lv;
    hv.x = f2bh(v.x); lv.x = f2bh(v.x - bh2f(hv.x));
    hv.y = f2bh(v.y); lv.y = f2bh(v.y - bh2f(hv.y));
    hv.z = f2bh(v.z); lv.z = f2bh(v.z - bh2f(hv.z));
    hv.w = f2bh(v.w); lv.w = f2bh(v.w - bh2f(hv.w));
    *reinterpret_cast<ushort4*>(&CTXh[ob + j]) = hv;
    *reinterpret_cast<ushort4*>(&CTXl[ob + j]) = lv;
  }
}

// ============================================================================
extern "C" void kernel_launch(void* const* d_in, const int* in_sizes, int n_in,
                              void* d_out, int out_size, void* d_ws,
                              size_t ws_size, hipStream_t stream) {
  // setup_inputs order: x, w_k, w_q, w_v, w_o, b_o
  const float* x  = (const float*)d_in[0];
  const float* wk = (const float*)d_in[1];
  const float* wq = (const float*)d_in[2];
  const float* wv = (const float*)d_in[3];
  const float* wo = (const float*)d_in[4];
  const float* bo = (const float*)d_in[5];
  float* out = (float*)d_out;

  // Workspace layout (ushort elements). CTX aliases Vr (dead after
  // convert_vt). Total ~91 MiB.
  ushort* xh   = (ushort*)d_ws;
  ushort* xl   = xh + NELEM;
  ushort* WH   = xl + NELEM;          // 4 planes: q,k,v,o
  ushort* WL   = WH + 4 * (size_t)WELEM;
  ushort* QKV  = WL + 4 * (size_t)WELEM;  // [Qh][Ql][Kh][Kl][Vrh][Vrl]
  ushort* Qh   = QKV;
  ushort* Ql   = Qh + NELEM;
  ushort* Kh   = Ql + NELEM;
  ushort* Kl   = Kh + NELEM;
  ushort* Vrh  = Kl + NELEM;
  ushort* Vrl  = Vrh + NELEM;
  ushort* Vth  = Vrl + NELEM;
  ushort* Vtl  = Vth + NELEM;
  ushort* CTXh = Vrh;  // alias: Vr dead after convert_vt
  ushort* CTXl = Vrl;
  float* O_part = (float*)(Vtl + NELEM);        // 1344 slots x 64 x 64 fp32
  float* m_part = O_part + 1344 * (size_t)4096; // 1344 x 64
  float* l_part = m_part + 1344 * 64;

  dim3 blk(256);
  convert_x<<<dim3(NELEM / 4 / 256), blk, 0, stream>>>(x, xh, xl);
  convert_w<<<dim3(WELEM / 4 / 256, 1, 4), blk, 0, stream>>>(wq, wk, wv, wo,
                                                             WH, WL);
  gemm_qkv_bf3<<<dim3(D_MODEL / 64, S_LEN / 128, 3), blk, 0, stream>>>(
      xh, xl, WH, WL, QKV);
  convert_vt<<<dim3(S_LEN / 64, N_HEAD), blk, 0, stream>>>(Vrh, Vrl, Vth, Vtl);
  attn_mfma<<<dim3(160, N_HEAD), blk, 0, stream>>>(
      Qh, Ql, Kh, Kl, Vth, Vtl, CTXh, CTXl, O_part, m_part, l_part);
  attn_combine<<<dim3(32, N_HEAD), blk, 0, stream>>>(O_part, m_part, l_part,
                                                     CTXh, CTXl);
  gemm_out_bf3<<<dim3(D_MODEL / 64, S_LEN / 128, 1), blk, 0, stream>>>(
      CTXh, CTXl, WH + 3 * (size_t)WELEM, WL + 3 * (size_t)WELEM, bo, out);
}

// Round 8
// 345.622 us; speedup vs baseline: 1.2341x; 1.2341x over previous
//
#include <hip/hip_runtime.h>
#include <math.h>

// Problem constants (B=1)
#define S_LEN   4096
#define D_MODEL 768
#define N_HEAD  12
#define H_DIM   64
#define NELEM   (S_LEN * D_MODEL)    // 3,145,728
#define WELEM   (D_MODEL * D_MODEL)  // 589,824

typedef unsigned short ushort;
typedef __attribute__((ext_vector_type(8))) short short8;
typedef __attribute__((ext_vector_type(4))) float f32x4;

__device__ __forceinline__ ushort f2bh(float f) {
  unsigned u = __float_as_uint(f);
  u += 0x7fffu + ((u >> 16) & 1u);  // round-to-nearest-even
  return (ushort)(u >> 16);
}
__device__ __forceinline__ float bh2f(ushort h) {
  return __uint_as_float(((unsigned)h) << 16);
}

// XOR swizzle for 128B LDS rows: spreads 16B slots across banks.
#define SWZ(row, colByte) ((((row) * 128) + (colByte)) ^ (((row) & 7) << 4))

// ============================================================================
// convert_x: fp32 -> bf16 hi/lo planes (element-wise, 4/thread)
// ============================================================================
__global__ __launch_bounds__(256)
void convert_x(const float* __restrict__ x, ushort* __restrict__ xh,
               ushort* __restrict__ xl) {
  size_t i = ((size_t)blockIdx.x * 256 + threadIdx.x) * 4;
  float4 v = *reinterpret_cast<const float4*>(&x[i]);
  ushort4 hv, lv;
  hv.x = f2bh(v.x); lv.x = f2bh(v.x - bh2f(hv.x));
  hv.y = f2bh(v.y); lv.y = f2bh(v.y - bh2f(hv.y));
  hv.z = f2bh(v.z); lv.z = f2bh(v.z - bh2f(hv.z));
  hv.w = f2bh(v.w); lv.w = f2bh(v.w - bh2f(hv.w));
  *reinterpret_cast<ushort4*>(&xh[i]) = hv;
  *reinterpret_cast<ushort4*>(&xl[i]) = lv;
}

// convert_w: 4 weight matrices -> hi/lo planes (plane z: 0=q,1=k,2=v,3=o)
__global__ __launch_bounds__(256)
void convert_w(const float* __restrict__ wq, const float* __restrict__ wk,
               const float* __restrict__ wv, const float* __restrict__ wo,
               ushort* __restrict__ WH, ushort* __restrict__ WL) {
  int z = blockIdx.z;
  const float* src = (z == 0) ? wq : (z == 1) ? wk : (z == 2) ? wv : wo;
  ushort* oh = WH + (size_t)z * WELEM;
  ushort* ol = WL + (size_t)z * WELEM;
  size_t i = ((size_t)blockIdx.x * 256 + threadIdx.x) * 4;
  float4 v = *reinterpret_cast<const float4*>(&src[i]);
  ushort4 hv, lv;
  hv.x = f2bh(v.x); lv.x = f2bh(v.x - bh2f(hv.x));
  hv.y = f2bh(v.y); lv.y = f2bh(v.y - bh2f(hv.y));
  hv.z = f2bh(v.z); lv.z = f2bh(v.z - bh2f(hv.z));
  hv.w = f2bh(v.w); lv.w = f2bh(v.w - bh2f(hv.w));
  *reinterpret_cast<ushort4*>(&oh[i]) = hv;
  *reinterpret_cast<ushort4*>(&ol[i]) = lv;
}

// ============================================================================
// bf16x3 MFMA GEMM core: C[128x64] += A(hi+lo) * W(hi+lo)^T
// 256 thr = 4 waves (2x2); wave = 64x32 sub-tile = 4x2 16x16 frags.
// BK=64, swizzled LDS. T14 prefetch in NAMED registers (arrays/lambdas go to
// scratch -- R3 lesson: 500MB HBM writes).
// ============================================================================
__device__ __forceinline__ void gemm_bf3_core(
    const ushort* __restrict__ Ah, const ushort* __restrict__ Al,
    const ushort* __restrict__ Wh, const ushort* __restrict__ Wl,
    int rowbase, int colbase, f32x4 (&acc)[4][2]) {
  __shared__ __align__(16) ushort AhS[128 * 64];
  __shared__ __align__(16) ushort AlS[128 * 64];
  __shared__ __align__(16) ushort WhS[64 * 64];
  __shared__ __align__(16) ushort WlS[64 * 64];
  char* AhB = (char*)AhS; char* AlB = (char*)AlS;
  char* WhB = (char*)WhS; char* WlB = (char*)WlS;

  const int tid  = threadIdx.x;
  const int lane = tid & 63;
  const int w    = tid >> 6;
  const int wm   = w >> 1;
  const int wn   = w & 1;
  const int lr   = lane & 15;
  const int lk   = lane >> 4;

  const int r0 = tid >> 3;          // 0..31
  const int cb = (tid & 7) * 16;    // byte col in LDS row
  const int ce = (tid & 7) * 8;     // element col
  const int sA0 = SWZ(r0, cb);
  const int sA1 = SWZ(r0 + 32, cb);
  const int sA2 = SWZ(r0 + 64, cb);
  const int sA3 = SWZ(r0 + 96, cb);

#pragma unroll
  for (int mt = 0; mt < 4; ++mt)
#pragma unroll
    for (int nt = 0; nt < 2; ++nt) acc[mt][nt] = {0.f, 0.f, 0.f, 0.f};

  // Named prefetch registers (A: 4 row-groups x hi/lo; W: 2 x hi/lo).
  float4 gA0h, gA1h, gA2h, gA3h, gA0l, gA1l, gA2l, gA3l;
  float4 gW0h, gW1h, gW0l, gW1l;

#define GEMM_ISSUE(k0_)                                                     \
  {                                                                         \
    size_t oA = (size_t)(rowbase + r0) * D_MODEL + (k0_) + ce;              \
    const size_t st = 32 * (size_t)D_MODEL;                                 \
    gA0h = *reinterpret_cast<const float4*>(Ah + oA);                       \
    gA1h = *reinterpret_cast<const float4*>(Ah + oA + st);                  \
    gA2h = *reinterpret_cast<const float4*>(Ah + oA + 2 * st);              \
    gA3h = *reinterpret_cast<const float4*>(Ah + oA + 3 * st);              \
    gA0l = *reinterpret_cast<const float4*>(Al + oA);                       \
    gA1l = *reinterpret_cast<const float4*>(Al + oA + st);                  \
    gA2l = *reinterpret_cast<const float4*>(Al + oA + 2 * st);              \
    gA3l = *reinterpret_cast<const float4*>(Al + oA + 3 * st);              \
    size_t oW = (size_t)(colbase + r0) * D_MODEL + (k0_) + ce;              \
    gW0h = *reinterpret_cast<const float4*>(Wh + oW);                       \
    gW1h = *reinterpret_cast<const float4*>(Wh + oW + st);                  \
    gW0l = *reinterpret_cast<const float4*>(Wl + oW);                       \
    gW1l = *reinterpret_cast<const float4*>(Wl + oW + st);                  \
  }

  GEMM_ISSUE(0);
  for (int ks = 0; ks < D_MODEL / 64; ++ks) {
    __syncthreads();  // prior compute done reading LDS
    *reinterpret_cast<float4*>(AhB + sA0) = gA0h;
    *reinterpret_cast<float4*>(AhB + sA1) = gA1h;
    *reinterpret_cast<float4*>(AhB + sA2) = gA2h;
    *reinterpret_cast<float4*>(AhB + sA3) = gA3h;
    *reinterpret_cast<float4*>(AlB + sA0) = gA0l;
    *reinterpret_cast<float4*>(AlB + sA1) = gA1l;
    *reinterpret_cast<float4*>(AlB + sA2) = gA2l;
    *reinterpret_cast<float4*>(AlB + sA3) = gA3l;
    *reinterpret_cast<float4*>(WhB + sA0) = gW0h;
    *reinterpret_cast<float4*>(WhB + sA1) = gW1h;
    *reinterpret_cast<float4*>(WlB + sA0) = gW0l;
    *reinterpret_cast<float4*>(WlB + sA1) = gW1l;
    __syncthreads();
    if (ks < D_MODEL / 64 - 1) GEMM_ISSUE((ks + 1) * 64);  // hide under MFMA

#pragma unroll
    for (int kc = 0; kc < 2; ++kc) {
      short8 ah[4], al[4], bh[2], bl[2];
#pragma unroll
      for (int mt = 0; mt < 4; ++mt) {
        int o = SWZ(wm * 64 + mt * 16 + lr, kc * 64 + lk * 16);
        ah[mt] = *reinterpret_cast<const short8*>(AhB + o);
        al[mt] = *reinterpret_cast<const short8*>(AlB + o);
      }
#pragma unroll
      for (int nt = 0; nt < 2; ++nt) {
        int o = SWZ(wn * 32 + nt * 16 + lr, kc * 64 + lk * 16);
        bh[nt] = *reinterpret_cast<const short8*>(WhB + o);
        bl[nt] = *reinterpret_cast<const short8*>(WlB + o);
      }
#pragma unroll
      for (int mt = 0; mt < 4; ++mt)
#pragma unroll
        for (int nt = 0; nt < 2; ++nt) {
          acc[mt][nt] = __builtin_amdgcn_mfma_f32_16x16x32_bf16(
              ah[mt], bh[nt], acc[mt][nt], 0, 0, 0);
          acc[mt][nt] = __builtin_amdgcn_mfma_f32_16x16x32_bf16(
              al[mt], bh[nt], acc[mt][nt], 0, 0, 0);
          acc[mt][nt] = __builtin_amdgcn_mfma_f32_16x16x32_bf16(
              ah[mt], bl[nt], acc[mt][nt], 0, 0, 0);
        }
    }
  }
#undef GEMM_ISSUE
}

// QKV projections: grid (12, 32, 3); z: 0=Q(scale (1/8)/ln2), 1=K, 2=V.
// Q pre-scaled so softmax runs in exp2 domain (native v_exp_f32).
__global__ __launch_bounds__(256)
void gemm_qkv_bf3(const ushort* __restrict__ xh, const ushort* __restrict__ xl,
                  const ushort* __restrict__ WH, const ushort* __restrict__ WL,
                  ushort* __restrict__ QKV) {
  const int z = blockIdx.z;
  const ushort* Wh = WH + (size_t)z * WELEM;
  const ushort* Wl = WL + (size_t)z * WELEM;
  ushort* oh = QKV + (size_t)z * (2 * NELEM);
  ushort* ol = oh + NELEM;
  const float scale = (z == 0) ? 0.125f * 1.44269504089f : 1.0f;
  const int rowbase = blockIdx.y * 128;
  const int colbase = blockIdx.x * 64;

  f32x4 acc[4][2];
  gemm_bf3_core(xh, xl, Wh, Wl, rowbase, colbase, acc);

  const int lane = threadIdx.x & 63, w = threadIdx.x >> 6;
  const int wm = w >> 1, wn = w & 1, lr = lane & 15, lk = lane >> 4;
#pragma unroll
  for (int mt = 0; mt < 4; ++mt)
#pragma unroll
    for (int nt = 0; nt < 2; ++nt)
#pragma unroll
      for (int j = 0; j < 4; ++j) {
        int rg = rowbase + wm * 64 + mt * 16 + lk * 4 + j;
        int cg = colbase + wn * 32 + nt * 16 + lr;
        float v = acc[mt][nt][j] * scale;
        ushort hh = f2bh(v);
        oh[(size_t)rg * D_MODEL + cg] = hh;
        ol[(size_t)rg * D_MODEL + cg] = f2bh(v - bh2f(hh));
      }
}

// Output projection: fp32 out + bias.
__global__ __launch_bounds__(256)
void gemm_out_bf3(const ushort* __restrict__ ch, const ushort* __restrict__ cl,
                  const ushort* __restrict__ woh, const ushort* __restrict__ wol,
                  const float* __restrict__ bo, float* __restrict__ out) {
  const int rowbase = blockIdx.y * 128;
  const int colbase = blockIdx.x * 64;
  f32x4 acc[4][2];
  gemm_bf3_core(ch, cl, woh, wol, rowbase, colbase, acc);

  const int lane = threadIdx.x & 63, w = threadIdx.x >> 6;
  const int wm = w >> 1, wn = w & 1, lr = lane & 15, lk = lane >> 4;
#pragma unroll
  for (int nt = 0; nt < 2; ++nt) {
    int cg = colbase + wn * 32 + nt * 16 + lr;
    float bb = bo[cg];
#pragma unroll
    for (int mt = 0; mt < 4; ++mt)
#pragma unroll
      for (int j = 0; j < 4; ++j) {
        int rg = rowbase + wm * 64 + mt * 16 + lk * 4 + j;
        out[(size_t)rg * D_MODEL + cg] = acc[mt][nt][j] + bb;
      }
  }
}

// ============================================================================
// V transpose: row-major hi/lo planes -> [h][d][s] hi/lo planes.
// ============================================================================
__global__ __launch_bounds__(256)
void convert_vt(const ushort* __restrict__ Vrh, const ushort* __restrict__ Vrl,
                ushort* __restrict__ Vth, ushort* __restrict__ Vtl) {
  __shared__ ushort th[64][68];
  __shared__ ushort tl[64][68];
  const int tid = threadIdx.x;
  const int s0  = blockIdx.x * 64;
  const int h   = blockIdx.y;
#pragma unroll
  for (int it = 0; it < 4; ++it) {
    int id = tid + it * 256;
    int s  = id >> 4;
    int c4 = (id & 15) * 4;
    size_t g = (size_t)(s0 + s) * D_MODEL + h * H_DIM + c4;
    ushort4 vh = *reinterpret_cast<const ushort4*>(&Vrh[g]);
    ushort4 vl = *reinterpret_cast<const ushort4*>(&Vrl[g]);
    th[c4 + 0][s] = vh.x; th[c4 + 1][s] = vh.y;
    th[c4 + 2][s] = vh.z; th[c4 + 3][s] = vh.w;
    tl[c4 + 0][s] = vl.x; tl[c4 + 1][s] = vl.y;
    tl[c4 + 2][s] = vl.z; tl[c4 + 3][s] = vl.w;
  }
  __syncthreads();
#pragma unroll
  for (int it = 0; it < 4; ++it) {
    int id = tid + it * 256;
    int d  = id >> 4;
    int s4 = (id & 15) * 4;
    ushort4 oh, ol;
    oh.x = th[d][s4 + 0]; oh.y = th[d][s4 + 1];
    oh.z = th[d][s4 + 2]; oh.w = th[d][s4 + 3];
    ol.x = tl[d][s4 + 0]; ol.y = tl[d][s4 + 1];
    ol.z = tl[d][s4 + 2]; ol.w = tl[d][s4 + 3];
    size_t o = (size_t)(h * H_DIM + d) * S_LEN + s0 + s4;
    *reinterpret_cast<ushort4*>(&Vth[o]) = oh;
    *reinterpret_cast<ushort4*>(&Vtl[o]) = ol;
  }
}

// ============================================================================
// Flash attention fwd (causal), bf16x3 MFMA (QK^T) + bf16x2 (PV, P-hi only),
// fp32 online softmax in exp2 domain, EQUAL-CHUNK SPLIT-K, heavy-first.
// Grid (160, 12), bx enumerates qb DESCENDING:
//   bx   0..63 : qb = 63-(bx>>2),      c = bx&3,          nch = 4
//   bx  64..111: qb = 47-(bx-64)/3,    c = (bx-64)%3,     nch = 3
//   bx 112..143: qb = 31-(bx-112)/2,   c = (bx-112)&1,    nch = 2
//   bx 144..159: qb = 159-bx (15..0),  direct CTX write,  nch = 1
// Chunk kt range: [c*(qb+1)/nch, (c+1)*(qb+1)/nch) -- lengths 8..16, no tails.
// Partial slot = h*144 + bx. LDS = 40960 B -> 4 blocks/CU.
// T13-exact rescale skip; l-reduction deferred to epilogue (saves 16 shfl/tile).
// ============================================================================
__global__ __launch_bounds__(256)
void attn_mfma(const ushort* __restrict__ Qh_g, const ushort* __restrict__ Ql_g,
               const ushort* __restrict__ Kh_g, const ushort* __restrict__ Kl_g,
               const ushort* __restrict__ Vh_g, const ushort* __restrict__ Vl_g,
               ushort* __restrict__ CTXh, ushort* __restrict__ CTXl,
               float* __restrict__ O_part, float* __restrict__ m_part,
               float* __restrict__ l_part) {
  const int bx = blockIdx.x;
  const int h  = blockIdx.y;
  int qb, c, nch, partial = 1;
  if (bx < 64)       { qb = 63 - (bx >> 2);        c = bx & 3;        nch = 4; }
  else if (bx < 112) { int off = bx - 64;  qb = 47 - off / 3; c = off % 3; nch = 3; }
  else if (bx < 144) { int off = bx - 112; qb = 31 - off / 2; c = off & 1; nch = 2; }
  else               { qb = 159 - bx; c = 0; nch = 1; partial = 0; }
  const int kt0 = c * (qb + 1) / nch;
  const int kt1 = (c + 1) * (qb + 1) / nch;
  const int slot = h * 144 + bx;

  __shared__ __align__(16) ushort Kh_s[64 * 64];
  __shared__ __align__(16) ushort Kl_s[64 * 64];
  __shared__ __align__(16) ushort Vh_s[64 * 64];
  __shared__ __align__(16) ushort Vl_s[64 * 64];
  __shared__ __align__(16) ushort P_s[4][16 * 64];  // per-wave P hi, swizzled

  char* KhB = (char*)Kh_s;
  char* KlB = (char*)Kl_s;
  char* VhB = (char*)Vh_s;
  char* VlB = (char*)Vl_s;

  const int tid  = threadIdx.x;
  const int lane = tid & 63;
  const int w    = tid >> 6;
  const int lr   = lane & 15;
  const int lk   = lane >> 4;
  const float NEG = -1e30f;

  const int r0 = tid >> 3;          // 0..31
  const int cb = (tid & 7) * 16;
  const int ce = (tid & 7) * 8;
  const int swA = SWZ(r0, cb);
  const int swB = SWZ(r0 + 32, cb);

  // ---- Prologue: stage Q tile through K buffers, hoist A-frags to regs ----
  {
    size_t g0 = (size_t)(qb * 64 + r0) * D_MODEL + h * H_DIM + ce;
    size_t g1 = g0 + 32 * (size_t)D_MODEL;
    *reinterpret_cast<float4*>(KhB + swA) =
        *reinterpret_cast<const float4*>(Qh_g + g0);
    *reinterpret_cast<float4*>(KhB + swB) =
        *reinterpret_cast<const float4*>(Qh_g + g1);
    *reinterpret_cast<float4*>(KlB + swA) =
        *reinterpret_cast<const float4*>(Ql_g + g0);
    *reinterpret_cast<float4*>(KlB + swB) =
        *reinterpret_cast<const float4*>(Ql_g + g1);
  }
  __syncthreads();
  short8 aqh[2], aql[2];
#pragma unroll
  for (int kc = 0; kc < 2; ++kc) {
    int ao = SWZ(w * 16 + lr, kc * 64 + lk * 16);
    aqh[kc] = *reinterpret_cast<const short8*>(KhB + ao);
    aql[kc] = *reinterpret_cast<const short8*>(KlB + ao);
  }

  f32x4 o[4];
  float m[4], l[4];  // l = per-lane partial sums (deferred reduce)
#pragma unroll
  for (int t = 0; t < 4; ++t) o[t] = {0.f, 0.f, 0.f, 0.f};
#pragma unroll
  for (int r = 0; r < 4; ++r) { m[r] = NEG; l[r] = 0.f; }

  // T14 prefetch: named registers only.
  float4 gkh0, gkh1, gkl0, gkl1, gvh0, gvh1, gvl0, gvl1;

#define ATTN_ISSUE(kt_)                                                     \
  {                                                                         \
    size_t gk0 = (size_t)((kt_) * 64 + r0) * D_MODEL + h * H_DIM + ce;      \
    size_t gk1 = gk0 + 32 * (size_t)D_MODEL;                                \
    size_t gv0 = (size_t)(h * H_DIM + r0) * S_LEN + (kt_) * 64 + ce;        \
    size_t gv1 = gv0 + 32 * (size_t)S_LEN;                                  \
    gkh0 = *reinterpret_cast<const float4*>(Kh_g + gk0);                    \
    gkh1 = *reinterpret_cast<const float4*>(Kh_g + gk1);                    \
    gkl0 = *reinterpret_cast<const float4*>(Kl_g + gk0);                    \
    gkl1 = *reinterpret_cast<const float4*>(Kl_g + gk1);                    \
    gvh0 = *reinterpret_cast<const float4*>(Vh_g + gv0);                    \
    gvh1 = *reinterpret_cast<const float4*>(Vh_g + gv1);                    \
    gvl0 = *reinterpret_cast<const float4*>(Vl_g + gv0);                    \
    gvl1 = *reinterpret_cast<const float4*>(Vl_g + gv1);                    \
  }

  ATTN_ISSUE(kt0);

  for (int kt = kt0; kt < kt1; ++kt) {
    __syncthreads();  // prior tile's LDS reads done (covers Q-frag reads too)
    *reinterpret_cast<float4*>(KhB + swA) = gkh0;
    *reinterpret_cast<float4*>(KhB + swB) = gkh1;
    *reinterpret_cast<float4*>(KlB + swA) = gkl0;
    *reinterpret_cast<float4*>(KlB + swB) = gkl1;
    *reinterpret_cast<float4*>(VhB + swA) = gvh0;
    *reinterpret_cast<float4*>(VhB + swB) = gvh1;
    *reinterpret_cast<float4*>(VlB + swA) = gvl0;
    *reinterpret_cast<float4*>(VlB + swB) = gvl1;
    __syncthreads();
    if (kt + 1 < kt1) ATTN_ISSUE(kt + 1);  // in flight during compute

    // ---- S' = Q K^T / (8 ln2)  (bf16x3; Q pre-scaled) ----
    f32x4 sacc[4];
#pragma unroll
    for (int t = 0; t < 4; ++t) sacc[t] = {0.f, 0.f, 0.f, 0.f};
#pragma unroll
    for (int kc = 0; kc < 2; ++kc) {
#pragma unroll
      for (int t = 0; t < 4; ++t) {
        int bo = SWZ(t * 16 + lr, kc * 64 + lk * 16);
        short8 bh = *reinterpret_cast<const short8*>(KhB + bo);
        short8 bl = *reinterpret_cast<const short8*>(KlB + bo);
        sacc[t] = __builtin_amdgcn_mfma_f32_16x16x32_bf16(aqh[kc], bh, sacc[t], 0, 0, 0);
        sacc[t] = __builtin_amdgcn_mfma_f32_16x16x32_bf16(aql[kc], bh, sacc[t], 0, 0, 0);
        sacc[t] = __builtin_amdgcn_mfma_f32_16x16x32_bf16(aqh[kc], bl, sacc[t], 0, 0, 0);
      }
    }

    // ---- causal mask on the diagonal tile ----
    if (kt == qb) {
#pragma unroll
      for (int t = 0; t < 4; ++t) {
        int colg = t * 16 + lr;
#pragma unroll
        for (int r = 0; r < 4; ++r) {
          int rowg = w * 16 + lk * 4 + r;
          if (colg > rowg) sacc[t][r] = NEG;
        }
      }
    }

    // ---- online softmax, exp2 domain; T13-exact rescale skip;
    //      l kept as per-lane partials (reduced once in epilogue) ----
    float pf[4][4];  // [t][r]
#pragma unroll
    for (int r = 0; r < 4; ++r) {
      float mx = fmaxf(fmaxf(sacc[0][r], sacc[1][r]),
                       fmaxf(sacc[2][r], sacc[3][r]));
      mx = fmaxf(mx, __shfl_xor(mx, 1));
      mx = fmaxf(mx, __shfl_xor(mx, 2));
      mx = fmaxf(mx, __shfl_xor(mx, 4));
      mx = fmaxf(mx, __shfl_xor(mx, 8));
      if (__any(mx > m[r])) {  // rescale only if some row's max grew (exact)
        float mnew  = fmaxf(m[r], mx);
        float alpha = exp2f(m[r] - mnew);
        m[r] = mnew;
        l[r] *= alpha;       // alpha is uniform within the 16-lane group
#pragma unroll
        for (int t = 0; t < 4; ++t) o[t][r] *= alpha;
      }
      float p0 = exp2f(sacc[0][r] - m[r]);
      float p1 = exp2f(sacc[1][r] - m[r]);
      float p2 = exp2f(sacc[2][r] - m[r]);
      float p3 = exp2f(sacc[3][r] - m[r]);
      pf[0][r] = p0; pf[1][r] = p1; pf[2][r] = p2; pf[3][r] = p3;
      l[r] += (p0 + p1) + (p2 + p3);
    }

    // ---- P(hi only) -> per-wave swizzled u16 LDS ----
    char* pwB = (char*)P_s[w];
#pragma unroll
    for (int r = 0; r < 4; ++r) {
      int prow = lk * 4 + r;
#pragma unroll
      for (int t = 0; t < 4; ++t) {
        int off = SWZ(prow, (t * 16 + lr) * 2);
        *reinterpret_cast<ushort*>(pwB + off) = f2bh(pf[t][r]);
      }
    }

    // ---- O += P V (P-hi x (Vh+Vl): 2 MFMAs per (kc,t)) ----
#pragma unroll
    for (int kc = 0; kc < 2; ++kc) {
      short8 pa = *reinterpret_cast<const short8*>(
          pwB + SWZ(lr, kc * 64 + lk * 16));
#pragma unroll
      for (int t = 0; t < 4; ++t) {
        int bo = SWZ(t * 16 + lr, kc * 64 + lk * 16);
        short8 vh = *reinterpret_cast<const short8*>(VhB + bo);
        short8 vl = *reinterpret_cast<const short8*>(VlB + bo);
        o[t] = __builtin_amdgcn_mfma_f32_16x16x32_bf16(pa, vh, o[t], 0, 0, 0);
        o[t] = __builtin_amdgcn_mfma_f32_16x16x32_bf16(pa, vl, o[t], 0, 0, 0);
      }
    }
  }
#undef ATTN_ISSUE

  // ---- deferred l reduction across the 16-lane group ----
#pragma unroll
  for (int r = 0; r < 4; ++r) {
    l[r] += __shfl_xor(l[r], 1);
    l[r] += __shfl_xor(l[r], 2);
    l[r] += __shfl_xor(l[r], 4);
    l[r] += __shfl_xor(l[r], 8);
  }

  if (!partial) {
    // ---- direct epilogue: normalize, store ctx as hi/lo bf16 planes ----
    float inv[4];
#pragma unroll
    for (int r = 0; r < 4; ++r) inv[r] = 1.f / l[r];
#pragma unroll
    for (int t = 0; t < 4; ++t)
#pragma unroll
      for (int r = 0; r < 4; ++r) {
        size_t idx = (size_t)(qb * 64 + w * 16 + lk * 4 + r) * D_MODEL +
                     h * H_DIM + t * 16 + lr;
        float v = o[t][r] * inv[r];
        ushort hh = f2bh(v);
        CTXh[idx] = hh;
        CTXl[idx] = f2bh(v - bh2f(hh));
      }
  } else {
    // ---- partial epilogue: unnormalized fp32 O + m + l (m in log2) ----
    float* Ob = O_part + (size_t)slot * 4096;
#pragma unroll
    for (int t = 0; t < 4; ++t)
#pragma unroll
      for (int r = 0; r < 4; ++r)
        Ob[(w * 16 + lk * 4 + r) * 64 + t * 16 + lr] = o[t][r];
    if (lr == 0) {
#pragma unroll
      for (int r = 0; r < 4; ++r) {
        int row = w * 16 + lk * 4 + r;
        m_part[slot * 64 + row] = m[r];
        l_part[slot * 64 + row] = l[r];
      }
    }
  }
}

// ============================================================================
// Combine 2-4 partials per (h, qb>=16): O = sum O_c 2^(m_c-M); ctx = O/L.
// Grid (48, 12), 256 threads; thread handles (row, 16 dims). Absent chunks
// read slot sb (in-bounds) with weight 0.
// Slot bases mirror the dispatch enumeration (slot = h*144 + bx):
//   qb>=48: sb=(63-qb)*4, nch=4 | qb>=32: sb=64+(47-qb)*3, nch=3
//   qb>=16: sb=112+(31-qb)*2, nch=2
// ============================================================================
__global__ __launch_bounds__(256)
void attn_combine(const float* __restrict__ O_part,
                  const float* __restrict__ m_part,
                  const float* __restrict__ l_part,
                  ushort* __restrict__ CTXh, ushort* __restrict__ CTXl) {
  const int qb  = 16 + blockIdx.x;  // 16..63
  const int h   = blockIdx.y;
  const int tid = threadIdx.x;
  const int row = tid >> 2;        // 0..63
  const int d0  = (tid & 3) * 16;  // 0,16,32,48
  int nch, sbl;
  if (qb >= 48)      { nch = 4; sbl = (63 - qb) * 4; }
  else if (qb >= 32) { nch = 3; sbl = 64 + (47 - qb) * 3; }
  else               { nch = 2; sbl = 112 + (31 - qb) * 2; }
  const int sb = h * 144 + sbl;
  const int s2 = (nch >= 3) ? sb + 2 : sb;
  const int s3 = (nch >= 4) ? sb + 3 : sb;

  float m0 = m_part[(sb + 0) * 64 + row];
  float m1 = m_part[(sb + 1) * 64 + row];
  float m2 = (nch >= 3) ? m_part[s2 * 64 + row] : -1e30f;
  float m3 = (nch >= 4) ? m_part[s3 * 64 + row] : -1e30f;
  float l0 = l_part[(sb + 0) * 64 + row];
  float l1 = l_part[(sb + 1) * 64 + row];
  float l2 = (nch >= 3) ? l_part[s2 * 64 + row] : 0.f;
  float l3 = (nch >= 4) ? l_part[s3 * 64 + row] : 0.f;
  float M  = fmaxf(fmaxf(m0, m1), fmaxf(m2, m3));
  float a0 = exp2f(m0 - M);
  float a1 = exp2f(m1 - M);
  float a2 = (nch >= 3) ? exp2f(m2 - M) : 0.f;
  float a3 = (nch >= 4) ? exp2f(m3 - M) : 0.f;
  float inv = 1.0f / (l0 * a0 + l1 * a1 + l2 * a2 + l3 * a3);

  const float* p0 = O_part + (size_t)(sb + 0) * 4096 + row * 64 + d0;
  const float* p1 = O_part + (size_t)(sb + 1) * 4096 + row * 64 + d0;
  const float* p2 = O_part + (size_t)s2 * 4096 + row * 64 + d0;
  const float* p3 = O_part + (size_t)s3 * 4096 + row * 64 + d0;
  size_t ob = (size_t)(qb * 64 + row) * D_MODEL + h * H_DIM + d0;
#pragma unroll
  for (int j = 0; j < 16; j += 4) {
    float4 x0 = *reinterpret_cast<const float4*>(p0 + j);
    float4 x1 = *reinterpret_cast<const float4*>(p1 + j);
    float4 x2 = *reinterpret_cast<const float4*>(p2 + j);
    float4 x3 = *reinterpret_cast<const float4*>(p3 + j);
    float4 v;
    v.x = (x0.x * a0 + x1.x * a1 + x2.x * a2 + x3.x * a3) * inv;
    v.y = (x0.y * a0 + x1.y * a1 + x2.y * a2 + x3.y * a3) * inv;
    v.z = (x0.z * a0 + x1.z * a1 + x2.z * a2 + x3.z * a3) * inv;
    v.w = (x0.w * a0 + x1.w * a1 + x2.w * a2 + x3.w * a3) * inv;
    ushort4 hv, lv;
    hv.x = f2bh(v.x); lv.x = f2bh(v.x - bh2f(hv.x));
    hv.y = f2bh(v.y); lv.y = f2bh(v.y - bh2f(hv.y));
    hv.z = f2bh(v.z); lv.z = f2bh(v.z - bh2f(hv.z));
    hv.w = f2bh(v.w); lv.w = f2bh(v.w - bh2f(hv.w));
    *reinterpret_cast<ushort4*>(&CTXh[ob + j]) = hv;
    *reinterpret_cast<ushort4*>(&CTXl[ob + j]) = lv;
  }
}

// ============================================================================
extern "C" void kernel_launch(void* const* d_in, const int* in_sizes, int n_in,
                              void* d_out, int out_size, void* d_ws,
                              size_t ws_size, hipStream_t stream) {
  // setup_inputs order: x, w_k, w_q, w_v, w_o, b_o
  const float* x  = (const float*)d_in[0];
  const float* wk = (const float*)d_in[1];
  const float* wq = (const float*)d_in[2];
  const float* wv = (const float*)d_in[3];
  const float* wo = (const float*)d_in[4];
  const float* bo = (const float*)d_in[5];
  float* out = (float*)d_out;

  // Workspace layout (ushort elements). CTX aliases Vr (dead after
  // convert_vt). Total ~101 MiB.
  ushort* xh   = (ushort*)d_ws;
  ushort* xl   = xh + NELEM;
  ushort* WH   = xl + NELEM;          // 4 planes: q,k,v,o
  ushort* WL   = WH + 4 * (size_t)WELEM;
  ushort* QKV  = WL + 4 * (size_t)WELEM;  // [Qh][Ql][Kh][Kl][Vrh][Vrl]
  ushort* Qh   = QKV;
  ushort* Ql   = Qh + NELEM;
  ushort* Kh   = Ql + NELEM;
  ushort* Kl   = Kh + NELEM;
  ushort* Vrh  = Kl + NELEM;
  ushort* Vrl  = Vrh + NELEM;
  ushort* Vth  = Vrl + NELEM;
  ushort* Vtl  = Vth + NELEM;
  ushort* CTXh = Vrh;  // alias: Vr dead after convert_vt
  ushort* CTXl = Vrl;
  float* O_part = (float*)(Vtl + NELEM);        // 1728 slots x 64 x 64 fp32
  float* m_part = O_part + 1728 * (size_t)4096; // 1728 x 64
  float* l_part = m_part + 1728 * 64;

  dim3 blk(256);
  convert_x<<<dim3(NELEM / 4 / 256), blk, 0, stream>>>(x, xh, xl);
  convert_w<<<dim3(WELEM / 4 / 256, 1, 4), blk, 0, stream>>>(wq, wk, wv, wo,
                                                             WH, WL);
  gemm_qkv_bf3<<<dim3(D_MODEL / 64, S_LEN / 128, 3), blk, 0, stream>>>(
      xh, xl, WH, WL, QKV);
  convert_vt<<<dim3(S_LEN / 64, N_HEAD), blk, 0, stream>>>(Vrh, Vrl, Vth, Vtl);
  attn_mfma<<<dim3(160, N_HEAD), blk, 0, stream>>>(
      Qh, Ql, Kh, Kl, Vth, Vtl, CTXh, CTXl, O_part, m_part, l_part);
  attn_combine<<<dim3(48, N_HEAD), blk, 0, stream>>>(O_part, m_part, l_part,
                                                     CTXh, CTXl);
  gemm_out_bf3<<<dim3(D_MODEL / 64, S_LEN / 128, 1), blk, 0, stream>>>(
      CTXh, CTXl, WH + 3 * (size_t)WELEM, WL + 3 * (size_t)WELEM, bo, out);
}

// Round 9
// 314.568 us; speedup vs baseline: 1.3559x; 1.0987x over previous
//
#include <hip/hip_runtime.h>
#include <math.h>

// Problem constants (B=1)
#define S_LEN   4096
#define D_MODEL 768
#define N_HEAD  12
#define H_DIM   64
#define NELEM   (S_LEN * D_MODEL)    // 3,145,728
#define WELEM   (D_MODEL * D_MODEL)  // 589,824

typedef unsigned short ushort;
typedef __attribute__((ext_vector_type(8))) short short8;
typedef __attribute__((ext_vector_type(4))) float f32x4;

__device__ __forceinline__ ushort f2bh(float f) {
  unsigned u = __float_as_uint(f);
  u += 0x7fffu + ((u >> 16) & 1u);  // round-to-nearest-even
  return (ushort)(u >> 16);
}
__device__ __forceinline__ float bh2f(ushort h) {
  return __uint_as_float(((unsigned)h) << 16);
}

// XOR swizzle for 128B LDS rows: spreads 16B slots across banks.
#define SWZ(row, colByte) ((((row) * 128) + (colByte)) ^ (((row) & 7) << 4))

// ============================================================================
// convert_x: fp32 -> bf16 hi/lo planes (element-wise, 4/thread)
// ============================================================================
__global__ __launch_bounds__(256)
void convert_x(const float* __restrict__ x, ushort* __restrict__ xh,
               ushort* __restrict__ xl) {
  size_t i = ((size_t)blockIdx.x * 256 + threadIdx.x) * 4;
  float4 v = *reinterpret_cast<const float4*>(&x[i]);
  ushort4 hv, lv;
  hv.x = f2bh(v.x); lv.x = f2bh(v.x - bh2f(hv.x));
  hv.y = f2bh(v.y); lv.y = f2bh(v.y - bh2f(hv.y));
  hv.z = f2bh(v.z); lv.z = f2bh(v.z - bh2f(hv.z));
  hv.w = f2bh(v.w); lv.w = f2bh(v.w - bh2f(hv.w));
  *reinterpret_cast<ushort4*>(&xh[i]) = hv;
  *reinterpret_cast<ushort4*>(&xl[i]) = lv;
}

// convert_w: 4 weight matrices -> hi/lo planes (plane z: 0=q,1=k,2=v,3=o)
__global__ __launch_bounds__(256)
void convert_w(const float* __restrict__ wq, const float* __restrict__ wk,
               const float* __restrict__ wv, const float* __restrict__ wo,
               ushort* __restrict__ WH, ushort* __restrict__ WL) {
  int z = blockIdx.z;
  const float* src = (z == 0) ? wq : (z == 1) ? wk : (z == 2) ? wv : wo;
  ushort* oh = WH + (size_t)z * WELEM;
  ushort* ol = WL + (size_t)z * WELEM;
  size_t i = ((size_t)blockIdx.x * 256 + threadIdx.x) * 4;
  float4 v = *reinterpret_cast<const float4*>(&src[i]);
  ushort4 hv, lv;
  hv.x = f2bh(v.x); lv.x = f2bh(v.x - bh2f(hv.x));
  hv.y = f2bh(v.y); lv.y = f2bh(v.y - bh2f(hv.y));
  hv.z = f2bh(v.z); lv.z = f2bh(v.z - bh2f(hv.z));
  hv.w = f2bh(v.w); lv.w = f2bh(v.w - bh2f(hv.w));
  *reinterpret_cast<ushort4*>(&oh[i]) = hv;
  *reinterpret_cast<ushort4*>(&ol[i]) = lv;
}

// ============================================================================
// bf16x3 MFMA GEMM core: C[128x64] += A(hi+lo) * W(hi+lo)^T
// 256 thr = 4 waves (2x2); wave = 64x32 sub-tile = 4x2 16x16 frags.
// BK=64, swizzled LDS. T14 prefetch in NAMED registers (arrays/lambdas go to
// scratch -- R3 lesson: 500MB HBM writes).
// ============================================================================
__device__ __forceinline__ void gemm_bf3_core(
    const ushort* __restrict__ Ah, const ushort* __restrict__ Al,
    const ushort* __restrict__ Wh, const ushort* __restrict__ Wl,
    int rowbase, int colbase, f32x4 (&acc)[4][2]) {
  __shared__ __align__(16) ushort AhS[128 * 64];
  __shared__ __align__(16) ushort AlS[128 * 64];
  __shared__ __align__(16) ushort WhS[64 * 64];
  __shared__ __align__(16) ushort WlS[64 * 64];
  char* AhB = (char*)AhS; char* AlB = (char*)AlS;
  char* WhB = (char*)WhS; char* WlB = (char*)WlS;

  const int tid  = threadIdx.x;
  const int lane = tid & 63;
  const int w    = tid >> 6;
  const int wm   = w >> 1;
  const int wn   = w & 1;
  const int lr   = lane & 15;
  const int lk   = lane >> 4;

  const int r0 = tid >> 3;          // 0..31
  const int cb = (tid & 7) * 16;    // byte col in LDS row
  const int ce = (tid & 7) * 8;     // element col
  const int sA0 = SWZ(r0, cb);
  const int sA1 = SWZ(r0 + 32, cb);
  const int sA2 = SWZ(r0 + 64, cb);
  const int sA3 = SWZ(r0 + 96, cb);

#pragma unroll
  for (int mt = 0; mt < 4; ++mt)
#pragma unroll
    for (int nt = 0; nt < 2; ++nt) acc[mt][nt] = {0.f, 0.f, 0.f, 0.f};

  // Named prefetch registers (A: 4 row-groups x hi/lo; W: 2 x hi/lo).
  float4 gA0h, gA1h, gA2h, gA3h, gA0l, gA1l, gA2l, gA3l;
  float4 gW0h, gW1h, gW0l, gW1l;

#define GEMM_ISSUE(k0_)                                                     \
  {                                                                         \
    size_t oA = (size_t)(rowbase + r0) * D_MODEL + (k0_) + ce;              \
    const size_t st = 32 * (size_t)D_MODEL;                                 \
    gA0h = *reinterpret_cast<const float4*>(Ah + oA);                       \
    gA1h = *reinterpret_cast<const float4*>(Ah + oA + st);                  \
    gA2h = *reinterpret_cast<const float4*>(Ah + oA + 2 * st);              \
    gA3h = *reinterpret_cast<const float4*>(Ah + oA + 3 * st);              \
    gA0l = *reinterpret_cast<const float4*>(Al + oA);                       \
    gA1l = *reinterpret_cast<const float4*>(Al + oA + st);                  \
    gA2l = *reinterpret_cast<const float4*>(Al + oA + 2 * st);              \
    gA3l = *reinterpret_cast<const float4*>(Al + oA + 3 * st);              \
    size_t oW = (size_t)(colbase + r0) * D_MODEL + (k0_) + ce;              \
    gW0h = *reinterpret_cast<const float4*>(Wh + oW);                       \
    gW1h = *reinterpret_cast<const float4*>(Wh + oW + st);                  \
    gW0l = *reinterpret_cast<const float4*>(Wl + oW);                       \
    gW1l = *reinterpret_cast<const float4*>(Wl + oW + st);                  \
  }

  GEMM_ISSUE(0);
  for (int ks = 0; ks < D_MODEL / 64; ++ks) {
    __syncthreads();  // prior compute done reading LDS
    *reinterpret_cast<float4*>(AhB + sA0) = gA0h;
    *reinterpret_cast<float4*>(AhB + sA1) = gA1h;
    *reinterpret_cast<float4*>(AhB + sA2) = gA2h;
    *reinterpret_cast<float4*>(AhB + sA3) = gA3h;
    *reinterpret_cast<float4*>(AlB + sA0) = gA0l;
    *reinterpret_cast<float4*>(AlB + sA1) = gA1l;
    *reinterpret_cast<float4*>(AlB + sA2) = gA2l;
    *reinterpret_cast<float4*>(AlB + sA3) = gA3l;
    *reinterpret_cast<float4*>(WhB + sA0) = gW0h;
    *reinterpret_cast<float4*>(WhB + sA1) = gW1h;
    *reinterpret_cast<float4*>(WlB + sA0) = gW0l;
    *reinterpret_cast<float4*>(WlB + sA1) = gW1l;
    __syncthreads();
    if (ks < D_MODEL / 64 - 1) GEMM_ISSUE((ks + 1) * 64);  // hide under MFMA

#pragma unroll
    for (int kc = 0; kc < 2; ++kc) {
      short8 ah[4], al[4], bh[2], bl[2];
#pragma unroll
      for (int mt = 0; mt < 4; ++mt) {
        int o = SWZ(wm * 64 + mt * 16 + lr, kc * 64 + lk * 16);
        ah[mt] = *reinterpret_cast<const short8*>(AhB + o);
        al[mt] = *reinterpret_cast<const short8*>(AlB + o);
      }
#pragma unroll
      for (int nt = 0; nt < 2; ++nt) {
        int o = SWZ(wn * 32 + nt * 16 + lr, kc * 64 + lk * 16);
        bh[nt] = *reinterpret_cast<const short8*>(WhB + o);
        bl[nt] = *reinterpret_cast<const short8*>(WlB + o);
      }
#pragma unroll
      for (int mt = 0; mt < 4; ++mt)
#pragma unroll
        for (int nt = 0; nt < 2; ++nt) {
          acc[mt][nt] = __builtin_amdgcn_mfma_f32_16x16x32_bf16(
              ah[mt], bh[nt], acc[mt][nt], 0, 0, 0);
          acc[mt][nt] = __builtin_amdgcn_mfma_f32_16x16x32_bf16(
              al[mt], bh[nt], acc[mt][nt], 0, 0, 0);
          acc[mt][nt] = __builtin_amdgcn_mfma_f32_16x16x32_bf16(
              ah[mt], bl[nt], acc[mt][nt], 0, 0, 0);
        }
    }
  }
#undef GEMM_ISSUE
}

// QKV projections: grid (12, 32, 3); z: 0=Q(scale (1/8)/ln2), 1=K, 2=V.
// Q pre-scaled so softmax runs in exp2 domain (native v_exp_f32).
__global__ __launch_bounds__(256)
void gemm_qkv_bf3(const ushort* __restrict__ xh, const ushort* __restrict__ xl,
                  const ushort* __restrict__ WH, const ushort* __restrict__ WL,
                  ushort* __restrict__ QKV) {
  const int z = blockIdx.z;
  const ushort* Wh = WH + (size_t)z * WELEM;
  const ushort* Wl = WL + (size_t)z * WELEM;
  ushort* oh = QKV + (size_t)z * (2 * NELEM);
  ushort* ol = oh + NELEM;
  const float scale = (z == 0) ? 0.125f * 1.44269504089f : 1.0f;
  const int rowbase = blockIdx.y * 128;
  const int colbase = blockIdx.x * 64;

  f32x4 acc[4][2];
  gemm_bf3_core(xh, xl, Wh, Wl, rowbase, colbase, acc);

  const int lane = threadIdx.x & 63, w = threadIdx.x >> 6;
  const int wm = w >> 1, wn = w & 1, lr = lane & 15, lk = lane >> 4;
#pragma unroll
  for (int mt = 0; mt < 4; ++mt)
#pragma unroll
    for (int nt = 0; nt < 2; ++nt)
#pragma unroll
      for (int j = 0; j < 4; ++j) {
        int rg = rowbase + wm * 64 + mt * 16 + lk * 4 + j;
        int cg = colbase + wn * 32 + nt * 16 + lr;
        float v = acc[mt][nt][j] * scale;
        ushort hh = f2bh(v);
        oh[(size_t)rg * D_MODEL + cg] = hh;
        ol[(size_t)rg * D_MODEL + cg] = f2bh(v - bh2f(hh));
      }
}

// Output projection: fp32 out + bias.
__global__ __launch_bounds__(256)
void gemm_out_bf3(const ushort* __restrict__ ch, const ushort* __restrict__ cl,
                  const ushort* __restrict__ woh, const ushort* __restrict__ wol,
                  const float* __restrict__ bo, float* __restrict__ out) {
  const int rowbase = blockIdx.y * 128;
  const int colbase = blockIdx.x * 64;
  f32x4 acc[4][2];
  gemm_bf3_core(ch, cl, woh, wol, rowbase, colbase, acc);

  const int lane = threadIdx.x & 63, w = threadIdx.x >> 6;
  const int wm = w >> 1, wn = w & 1, lr = lane & 15, lk = lane >> 4;
#pragma unroll
  for (int nt = 0; nt < 2; ++nt) {
    int cg = colbase + wn * 32 + nt * 16 + lr;
    float bb = bo[cg];
#pragma unroll
    for (int mt = 0; mt < 4; ++mt)
#pragma unroll
      for (int j = 0; j < 4; ++j) {
        int rg = rowbase + wm * 64 + mt * 16 + lk * 4 + j;
        out[(size_t)rg * D_MODEL + cg] = acc[mt][nt][j] + bb;
      }
  }
}

// ============================================================================
// V transpose: row-major hi/lo planes -> [h][d][s] hi/lo planes.
// ============================================================================
__global__ __launch_bounds__(256)
void convert_vt(const ushort* __restrict__ Vrh, const ushort* __restrict__ Vrl,
                ushort* __restrict__ Vth, ushort* __restrict__ Vtl) {
  __shared__ ushort th[64][68];
  __shared__ ushort tl[64][68];
  const int tid = threadIdx.x;
  const int s0  = blockIdx.x * 64;
  const int h   = blockIdx.y;
#pragma unroll
  for (int it = 0; it < 4; ++it) {
    int id = tid + it * 256;
    int s  = id >> 4;
    int c4 = (id & 15) * 4;
    size_t g = (size_t)(s0 + s) * D_MODEL + h * H_DIM + c4;
    ushort4 vh = *reinterpret_cast<const ushort4*>(&Vrh[g]);
    ushort4 vl = *reinterpret_cast<const ushort4*>(&Vrl[g]);
    th[c4 + 0][s] = vh.x; th[c4 + 1][s] = vh.y;
    th[c4 + 2][s] = vh.z; th[c4 + 3][s] = vh.w;
    tl[c4 + 0][s] = vl.x; tl[c4 + 1][s] = vl.y;
    tl[c4 + 2][s] = vl.z; tl[c4 + 3][s] = vl.w;
  }
  __syncthreads();
#pragma unroll
  for (int it = 0; it < 4; ++it) {
    int id = tid + it * 256;
    int d  = id >> 4;
    int s4 = (id & 15) * 4;
    ushort4 oh, ol;
    oh.x = th[d][s4 + 0]; oh.y = th[d][s4 + 1];
    oh.z = th[d][s4 + 2]; oh.w = th[d][s4 + 3];
    ol.x = tl[d][s4 + 0]; ol.y = tl[d][s4 + 1];
    ol.z = tl[d][s4 + 2]; ol.w = tl[d][s4 + 3];
    size_t o = (size_t)(h * H_DIM + d) * S_LEN + s0 + s4;
    *reinterpret_cast<ushort4*>(&Vth[o]) = oh;
    *reinterpret_cast<ushort4*>(&Vtl[o]) = ol;
  }
}

// ============================================================================
// Flash attention fwd (causal), bf16x3 MFMA (QK^T) + bf16x2 (PV, P-hi only),
// fp32 online softmax in exp2 domain, EQUAL-CHUNK SPLIT-K.
// Grid: 1-D, 1920 blocks. h = bx % 12 (FAST-varying -> all heads interleave;
// fixes R8's packing bug where head 11 ran alone at the end). i = bx / 12 is
// the chunk index in GLOBAL length-descending order:
//   i   0..7  : qb = 15-i, direct, full range (16..9 tiles -- long directs first)
//   i   8..151: j = i-8, partial chunks (R8 enumeration, slot = h*144 + j):
//     j   0..63 : qb = 63-(j>>2),     c = j&3,       nch = 4   (12-16 tiles)
//     j  64..111: qb = 47-(j-64)/3,   c = (j-64)%3,  nch = 3   (11-16 tiles)
//     j 112..143: qb = 31-(j-112)/2,  c = (j-112)&1, nch = 2   (8-16 tiles)
//   i 152..159: qb = 159-i, direct (7..0 -> 8..1 tiles, shortest last)
// Chunk kt range: [c*(qb+1)/nch, (c+1)*(qb+1)/nch). LDS 40960 B -> 4 blk/CU.
// T13-exact rescale skip; l-reduction deferred to epilogue.
// ============================================================================
__global__ __launch_bounds__(256)
void attn_mfma(const ushort* __restrict__ Qh_g, const ushort* __restrict__ Ql_g,
               const ushort* __restrict__ Kh_g, const ushort* __restrict__ Kl_g,
               const ushort* __restrict__ Vh_g, const ushort* __restrict__ Vl_g,
               ushort* __restrict__ CTXh, ushort* __restrict__ CTXl,
               float* __restrict__ O_part, float* __restrict__ m_part,
               float* __restrict__ l_part) {
  const int bxl = blockIdx.x;        // 0..1919
  const int h   = bxl % N_HEAD;      // fast-varying: heads interleave
  const int i   = bxl / N_HEAD;      // 0..159, global heavy-first order
  int qb, c = 0, nch = 1, slot = 0, partial = 0;
  if (i < 8) {
    qb = 15 - i;                     // long direct blocks first (16..9 tiles)
  } else if (i < 152) {
    int j = i - 8;
    if (j < 64)       { qb = 63 - (j >> 2);        c = j & 3;        nch = 4; }
    else if (j < 112) { int off = j - 64;  qb = 47 - off / 3; c = off % 3; nch = 3; }
    else              { int off = j - 112; qb = 31 - off / 2; c = off & 1; nch = 2; }
    partial = 1;
    slot = h * 144 + j;
  } else {
    qb = 159 - i;                    // shortest directs last (8..1 tiles)
  }
  const int kt0 = c * (qb + 1) / nch;
  const int kt1 = (c + 1) * (qb + 1) / nch;

  __shared__ __align__(16) ushort Kh_s[64 * 64];
  __shared__ __align__(16) ushort Kl_s[64 * 64];
  __shared__ __align__(16) ushort Vh_s[64 * 64];
  __shared__ __align__(16) ushort Vl_s[64 * 64];
  __shared__ __align__(16) ushort P_s[4][16 * 64];  // per-wave P hi, swizzled

  char* KhB = (char*)Kh_s;
  char* KlB = (char*)Kl_s;
  char* VhB = (char*)Vh_s;
  char* VlB = (char*)Vl_s;

  const int tid  = threadIdx.x;
  const int lane = tid & 63;
  const int w    = tid >> 6;
  const int lr   = lane & 15;
  const int lk   = lane >> 4;
  const float NEG = -1e30f;

  const int r0 = tid >> 3;          // 0..31
  const int cb = (tid & 7) * 16;
  const int ce = (tid & 7) * 8;
  const int swA = SWZ(r0, cb);
  const int swB = SWZ(r0 + 32, cb);

  // ---- Prologue: stage Q tile through K buffers, hoist A-frags to regs ----
  {
    size_t g0 = (size_t)(qb * 64 + r0) * D_MODEL + h * H_DIM + ce;
    size_t g1 = g0 + 32 * (size_t)D_MODEL;
    *reinterpret_cast<float4*>(KhB + swA) =
        *reinterpret_cast<const float4*>(Qh_g + g0);
    *reinterpret_cast<float4*>(KhB + swB) =
        *reinterpret_cast<const float4*>(Qh_g + g1);
    *reinterpret_cast<float4*>(KlB + swA) =
        *reinterpret_cast<const float4*>(Ql_g + g0);
    *reinterpret_cast<float4*>(KlB + swB) =
        *reinterpret_cast<const float4*>(Ql_g + g1);
  }
  __syncthreads();
  short8 aqh[2], aql[2];
#pragma unroll
  for (int kc = 0; kc < 2; ++kc) {
    int ao = SWZ(w * 16 + lr, kc * 64 + lk * 16);
    aqh[kc] = *reinterpret_cast<const short8*>(KhB + ao);
    aql[kc] = *reinterpret_cast<const short8*>(KlB + ao);
  }

  f32x4 o[4];
  float m[4], l[4];  // l = per-lane partial sums (deferred reduce)
#pragma unroll
  for (int t = 0; t < 4; ++t) o[t] = {0.f, 0.f, 0.f, 0.f};
#pragma unroll
  for (int r = 0; r < 4; ++r) { m[r] = NEG; l[r] = 0.f; }

  // T14 prefetch: named registers only.
  float4 gkh0, gkh1, gkl0, gkl1, gvh0, gvh1, gvl0, gvl1;

#define ATTN_ISSUE(kt_)                                                     \
  {                                                                         \
    size_t gk0 = (size_t)((kt_) * 64 + r0) * D_MODEL + h * H_DIM + ce;      \
    size_t gk1 = gk0 + 32 * (size_t)D_MODEL;                                \
    size_t gv0 = (size_t)(h * H_DIM + r0) * S_LEN + (kt_) * 64 + ce;        \
    size_t gv1 = gv0 + 32 * (size_t)S_LEN;                                  \
    gkh0 = *reinterpret_cast<const float4*>(Kh_g + gk0);                    \
    gkh1 = *reinterpret_cast<const float4*>(Kh_g + gk1);                    \
    gkl0 = *reinterpret_cast<const float4*>(Kl_g + gk0);                    \
    gkl1 = *reinterpret_cast<const float4*>(Kl_g + gk1);                    \
    gvh0 = *reinterpret_cast<const float4*>(Vh_g + gv0);                    \
    gvh1 = *reinterpret_cast<const float4*>(Vh_g + gv1);                    \
    gvl0 = *reinterpret_cast<const float4*>(Vl_g + gv0);                    \
    gvl1 = *reinterpret_cast<const float4*>(Vl_g + gv1);                    \
  }

  ATTN_ISSUE(kt0);

  for (int kt = kt0; kt < kt1; ++kt) {
    __syncthreads();  // prior tile's LDS reads done (covers Q-frag reads too)
    *reinterpret_cast<float4*>(KhB + swA) = gkh0;
    *reinterpret_cast<float4*>(KhB + swB) = gkh1;
    *reinterpret_cast<float4*>(KlB + swA) = gkl0;
    *reinterpret_cast<float4*>(KlB + swB) = gkl1;
    *reinterpret_cast<float4*>(VhB + swA) = gvh0;
    *reinterpret_cast<float4*>(VhB + swB) = gvh1;
    *reinterpret_cast<float4*>(VlB + swA) = gvl0;
    *reinterpret_cast<float4*>(VlB + swB) = gvl1;
    __syncthreads();
    if (kt + 1 < kt1) ATTN_ISSUE(kt + 1);  // in flight during compute

    // ---- S' = Q K^T / (8 ln2)  (bf16x3; Q pre-scaled) ----
    f32x4 sacc[4];
#pragma unroll
    for (int t = 0; t < 4; ++t) sacc[t] = {0.f, 0.f, 0.f, 0.f};
#pragma unroll
    for (int kc = 0; kc < 2; ++kc) {
#pragma unroll
      for (int t = 0; t < 4; ++t) {
        int bo = SWZ(t * 16 + lr, kc * 64 + lk * 16);
        short8 bh = *reinterpret_cast<const short8*>(KhB + bo);
        short8 bl = *reinterpret_cast<const short8*>(KlB + bo);
        sacc[t] = __builtin_amdgcn_mfma_f32_16x16x32_bf16(aqh[kc], bh, sacc[t], 0, 0, 0);
        sacc[t] = __builtin_amdgcn_mfma_f32_16x16x32_bf16(aql[kc], bh, sacc[t], 0, 0, 0);
        sacc[t] = __builtin_amdgcn_mfma_f32_16x16x32_bf16(aqh[kc], bl, sacc[t], 0, 0, 0);
      }
    }

    // ---- causal mask on the diagonal tile ----
    if (kt == qb) {
#pragma unroll
      for (int t = 0; t < 4; ++t) {
        int colg = t * 16 + lr;
#pragma unroll
        for (int r = 0; r < 4; ++r) {
          int rowg = w * 16 + lk * 4 + r;
          if (colg > rowg) sacc[t][r] = NEG;
        }
      }
    }

    // ---- online softmax, exp2 domain; T13-exact rescale skip;
    //      l kept as per-lane partials (reduced once in epilogue) ----
    float pf[4][4];  // [t][r]
#pragma unroll
    for (int r = 0; r < 4; ++r) {
      float mx = fmaxf(fmaxf(sacc[0][r], sacc[1][r]),
                       fmaxf(sacc[2][r], sacc[3][r]));
      mx = fmaxf(mx, __shfl_xor(mx, 1));
      mx = fmaxf(mx, __shfl_xor(mx, 2));
      mx = fmaxf(mx, __shfl_xor(mx, 4));
      mx = fmaxf(mx, __shfl_xor(mx, 8));
      if (__any(mx > m[r])) {  // rescale only if some row's max grew (exact)
        float mnew  = fmaxf(m[r], mx);
        float alpha = exp2f(m[r] - mnew);
        m[r] = mnew;
        l[r] *= alpha;       // alpha is uniform within the 16-lane group
#pragma unroll
        for (int t = 0; t < 4; ++t) o[t][r] *= alpha;
      }
      float p0 = exp2f(sacc[0][r] - m[r]);
      float p1 = exp2f(sacc[1][r] - m[r]);
      float p2 = exp2f(sacc[2][r] - m[r]);
      float p3 = exp2f(sacc[3][r] - m[r]);
      pf[0][r] = p0; pf[1][r] = p1; pf[2][r] = p2; pf[3][r] = p3;
      l[r] += (p0 + p1) + (p2 + p3);
    }

    // ---- P(hi only) -> per-wave swizzled u16 LDS ----
    char* pwB = (char*)P_s[w];
#pragma unroll
    for (int r = 0; r < 4; ++r) {
      int prow = lk * 4 + r;
#pragma unroll
      for (int t = 0; t < 4; ++t) {
        int off = SWZ(prow, (t * 16 + lr) * 2);
        *reinterpret_cast<ushort*>(pwB + off) = f2bh(pf[t][r]);
      }
    }

    // ---- O += P V (P-hi x (Vh+Vl): 2 MFMAs per (kc,t)) ----
#pragma unroll
    for (int kc = 0; kc < 2; ++kc) {
      short8 pa = *reinterpret_cast<const short8*>(
          pwB + SWZ(lr, kc * 64 + lk * 16));
#pragma unroll
      for (int t = 0; t < 4; ++t) {
        int bo = SWZ(t * 16 + lr, kc * 64 + lk * 16);
        short8 vh = *reinterpret_cast<const short8*>(VhB + bo);
        short8 vl = *reinterpret_cast<const short8*>(VlB + bo);
        o[t] = __builtin_amdgcn_mfma_f32_16x16x32_bf16(pa, vh, o[t], 0, 0, 0);
        o[t] = __builtin_amdgcn_mfma_f32_16x16x32_bf16(pa, vl, o[t], 0, 0, 0);
      }
    }
  }
#undef ATTN_ISSUE

  // ---- deferred l reduction across the 16-lane group ----
#pragma unroll
  for (int r = 0; r < 4; ++r) {
    l[r] += __shfl_xor(l[r], 1);
    l[r] += __shfl_xor(l[r], 2);
    l[r] += __shfl_xor(l[r], 4);
    l[r] += __shfl_xor(l[r], 8);
  }

  if (!partial) {
    // ---- direct epilogue: normalize, store ctx as hi/lo bf16 planes ----
    float inv[4];
#pragma unroll
    for (int r = 0; r < 4; ++r) inv[r] = 1.f / l[r];
#pragma unroll
    for (int t = 0; t < 4; ++t)
#pragma unroll
      for (int r = 0; r < 4; ++r) {
        size_t idx = (size_t)(qb * 64 + w * 16 + lk * 4 + r) * D_MODEL +
                     h * H_DIM + t * 16 + lr;
        float v = o[t][r] * inv[r];
        ushort hh = f2bh(v);
        CTXh[idx] = hh;
        CTXl[idx] = f2bh(v - bh2f(hh));
      }
  } else {
    // ---- partial epilogue: unnormalized fp32 O + m + l (m in log2) ----
    float* Ob = O_part + (size_t)slot * 4096;
#pragma unroll
    for (int t = 0; t < 4; ++t)
#pragma unroll
      for (int r = 0; r < 4; ++r)
        Ob[(w * 16 + lk * 4 + r) * 64 + t * 16 + lr] = o[t][r];
    if (lr == 0) {
#pragma unroll
      for (int r = 0; r < 4; ++r) {
        int row = w * 16 + lk * 4 + r;
        m_part[slot * 64 + row] = m[r];
        l_part[slot * 64 + row] = l[r];
      }
    }
  }
}

// ============================================================================
// Combine 2-4 partials per (h, qb>=16): O = sum O_c 2^(m_c-M); ctx = O/L.
// Grid (48, 12), 256 threads; thread handles (row, 16 dims). Absent chunks
// read slot sb (in-bounds) with weight 0.
// Slot bases mirror the partial enumeration (slot = h*144 + j):
//   qb>=48: sb=(63-qb)*4, nch=4 | qb>=32: sb=64+(47-qb)*3, nch=3
//   qb>=16: sb=112+(31-qb)*2, nch=2
// ============================================================================
__global__ __launch_bounds__(256)
void attn_combine(const float* __restrict__ O_part,
                  const float* __restrict__ m_part,
                  const float* __restrict__ l_part,
                  ushort* __restrict__ CTXh, ushort* __restrict__ CTXl) {
  const int qb  = 16 + blockIdx.x;  // 16..63
  const int h   = blockIdx.y;
  const int tid = threadIdx.x;
  const int row = tid >> 2;        // 0..63
  const int d0  = (tid & 3) * 16;  // 0,16,32,48
  int nch, sbl;
  if (qb >= 48)      { nch = 4; sbl = (63 - qb) * 4; }
  else if (qb >= 32) { nch = 3; sbl = 64 + (47 - qb) * 3; }
  else               { nch = 2; sbl = 112 + (31 - qb) * 2; }
  const int sb = h * 144 + sbl;
  const int s2 = (nch >= 3) ? sb + 2 : sb;
  const int s3 = (nch >= 4) ? sb + 3 : sb;

  float m0 = m_part[(sb + 0) * 64 + row];
  float m1 = m_part[(sb + 1) * 64 + row];
  float m2 = (nch >= 3) ? m_part[s2 * 64 + row] : -1e30f;
  float m3 = (nch >= 4) ? m_part[s3 * 64 + row] : -1e30f;
  float l0 = l_part[(sb + 0) * 64 + row];
  float l1 = l_part[(sb + 1) * 64 + row];
  float l2 = (nch >= 3) ? l_part[s2 * 64 + row] : 0.f;
  float l3 = (nch >= 4) ? l_part[s3 * 64 + row] : 0.f;
  float M  = fmaxf(fmaxf(m0, m1), fmaxf(m2, m3));
  float a0 = exp2f(m0 - M);
  float a1 = exp2f(m1 - M);
  float a2 = (nch >= 3) ? exp2f(m2 - M) : 0.f;
  float a3 = (nch >= 4) ? exp2f(m3 - M) : 0.f;
  float inv = 1.0f / (l0 * a0 + l1 * a1 + l2 * a2 + l3 * a3);

  const float* p0 = O_part + (size_t)(sb + 0) * 4096 + row * 64 + d0;
  const float* p1 = O_part + (size_t)(sb + 1) * 4096 + row * 64 + d0;
  const float* p2 = O_part + (size_t)s2 * 4096 + row * 64 + d0;
  const float* p3 = O_part + (size_t)s3 * 4096 + row * 64 + d0;
  size_t ob = (size_t)(qb * 64 + row) * D_MODEL + h * H_DIM + d0;
#pragma unroll
  for (int j = 0; j < 16; j += 4) {
    float4 x0 = *reinterpret_cast<const float4*>(p0 + j);
    float4 x1 = *reinterpret_cast<const float4*>(p1 + j);
    float4 x2 = *reinterpret_cast<const float4*>(p2 + j);
    float4 x3 = *reinterpret_cast<const float4*>(p3 + j);
    float4 v;
    v.x = (x0.x * a0 + x1.x * a1 + x2.x * a2 + x3.x * a3) * inv;
    v.y = (x0.y * a0 + x1.y * a1 + x2.y * a2 + x3.y * a3) * inv;
    v.z = (x0.z * a0 + x1.z * a1 + x2.z * a2 + x3.z * a3) * inv;
    v.w = (x0.w * a0 + x1.w * a1 + x2.w * a2 + x3.w * a3) * inv;
    ushort4 hv, lv;
    hv.x = f2bh(v.x); lv.x = f2bh(v.x - bh2f(hv.x));
    hv.y = f2bh(v.y); lv.y = f2bh(v.y - bh2f(hv.y));
    hv.z = f2bh(v.z); lv.z = f2bh(v.z - bh2f(hv.z));
    hv.w = f2bh(v.w); lv.w = f2bh(v.w - bh2f(hv.w));
    *reinterpret_cast<ushort4*>(&CTXh[ob + j]) = hv;
    *reinterpret_cast<ushort4*>(&CTXl[ob + j]) = lv;
  }
}

// ============================================================================
extern "C" void kernel_launch(void* const* d_in, const int* in_sizes, int n_in,
                              void* d_out, int out_size, void* d_ws,
                              size_t ws_size, hipStream_t stream) {
  // setup_inputs order: x, w_k, w_q, w_v, w_o, b_o
  const float* x  = (const float*)d_in[0];
  const float* wk = (const float*)d_in[1];
  const float* wq = (const float*)d_in[2];
  const float* wv = (const float*)d_in[3];
  const float* wo = (const float*)d_in[4];
  const float* bo = (const float*)d_in[5];
  float* out = (float*)d_out;

  // Workspace layout (ushort elements). CTX aliases Vr (dead after
  // convert_vt). Total ~101 MiB (same as R8).
  ushort* xh   = (ushort*)d_ws;
  ushort* xl   = xh + NELEM;
  ushort* WH   = xl + NELEM;          // 4 planes: q,k,v,o
  ushort* WL   = WH + 4 * (size_t)WELEM;
  ushort* QKV  = WL + 4 * (size_t)WELEM;  // [Qh][Ql][Kh][Kl][Vrh][Vrl]
  ushort* Qh   = QKV;
  ushort* Ql   = Qh + NELEM;
  ushort* Kh   = Ql + NELEM;
  ushort* Kl   = Kh + NELEM;
  ushort* Vrh  = Kl + NELEM;
  ushort* Vrl  = Vrh + NELEM;
  ushort* Vth  = Vrl + NELEM;
  ushort* Vtl  = Vth + NELEM;
  ushort* CTXh = Vrh;  // alias: Vr dead after convert_vt
  ushort* CTXl = Vrl;
  float* O_part = (float*)(Vtl + NELEM);        // 1728 slots x 64 x 64 fp32
  float* m_part = O_part + 1728 * (size_t)4096; // 1728 x 64
  float* l_part = m_part + 1728 * 64;

  dim3 blk(256);
  convert_x<<<dim3(NELEM / 4 / 256), blk, 0, stream>>>(x, xh, xl);
  convert_w<<<dim3(WELEM / 4 / 256, 1, 4), blk, 0, stream>>>(wq, wk, wv, wo,
                                                             WH, WL);
  gemm_qkv_bf3<<<dim3(D_MODEL / 64, S_LEN / 128, 3), blk, 0, stream>>>(
      xh, xl, WH, WL, QKV);
  convert_vt<<<dim3(S_LEN / 64, N_HEAD), blk, 0, stream>>>(Vrh, Vrl, Vth, Vtl);
  attn_mfma<<<dim3(160 * N_HEAD), blk, 0, stream>>>(
      Qh, Ql, Kh, Kl, Vth, Vtl, CTXh, CTXl, O_part, m_part, l_part);
  attn_combine<<<dim3(48, N_HEAD), blk, 0, stream>>>(O_part, m_part, l_part,
                                                     CTXh, CTXl);
  gemm_out_bf3<<<dim3(D_MODEL / 64, S_LEN / 128, 1), blk, 0, stream>>>(
      CTXh, CTXl, WH + 3 * (size_t)WELEM, WL + 3 * (size_t)WELEM, bo, out);
}

// Round 10
// 278.457 us; speedup vs baseline: 1.5317x; 1.1297x over previous
//
#include <hip/hip_runtime.h>
#include <math.h>

// Problem constants (B=1)
#define S_LEN   4096
#define D_MODEL 768
#define N_HEAD  12
#define H_DIM   64
#define NELEM   (S_LEN * D_MODEL)    // 3,145,728
#define WELEM   (D_MODEL * D_MODEL)  // 589,824

typedef unsigned short ushort;
typedef __attribute__((ext_vector_type(8))) short short8;
typedef __attribute__((ext_vector_type(4))) float f32x4;
typedef __attribute__((ext_vector_type(4))) int i32x4;

__device__ __forceinline__ ushort f2bh(float f) {
  unsigned u = __float_as_uint(f);
  u += 0x7fffu + ((u >> 16) & 1u);  // round-to-nearest-even
  return (ushort)(u >> 16);
}
__device__ __forceinline__ float bh2f(ushort h) {
  return __uint_as_float(((unsigned)h) << 16);
}
// Packed f32x2 -> bf16x2 (RNE), low = a, high = b.
__device__ __forceinline__ unsigned cvtpk_bf16(float a, float b) {
  unsigned r;
  asm("v_cvt_pk_bf16_f32 %0, %1, %2" : "=v"(r) : "v"(a), "v"(b));
  return r;
}

// XOR swizzle for 128B LDS rows: spreads 16B slots across banks.
#define SWZ(row, colByte) ((((row) * 128) + (colByte)) ^ (((row) & 7) << 4))

// ============================================================================
// convert_x: fp32 -> bf16 hi/lo planes (element-wise, 4/thread)
// ============================================================================
__global__ __launch_bounds__(256)
void convert_x(const float* __restrict__ x, ushort* __restrict__ xh,
               ushort* __restrict__ xl) {
  size_t i = ((size_t)blockIdx.x * 256 + threadIdx.x) * 4;
  float4 v = *reinterpret_cast<const float4*>(&x[i]);
  ushort4 hv, lv;
  hv.x = f2bh(v.x); lv.x = f2bh(v.x - bh2f(hv.x));
  hv.y = f2bh(v.y); lv.y = f2bh(v.y - bh2f(hv.y));
  hv.z = f2bh(v.z); lv.z = f2bh(v.z - bh2f(hv.z));
  hv.w = f2bh(v.w); lv.w = f2bh(v.w - bh2f(hv.w));
  *reinterpret_cast<ushort4*>(&xh[i]) = hv;
  *reinterpret_cast<ushort4*>(&xl[i]) = lv;
}

// convert_w: 4 weight matrices -> hi/lo planes (plane z: 0=q,1=k,2=v,3=o)
__global__ __launch_bounds__(256)
void convert_w(const float* __restrict__ wq, const float* __restrict__ wk,
               const float* __restrict__ wv, const float* __restrict__ wo,
               ushort* __restrict__ WH, ushort* __restrict__ WL) {
  int z = blockIdx.z;
  const float* src = (z == 0) ? wq : (z == 1) ? wk : (z == 2) ? wv : wo;
  ushort* oh = WH + (size_t)z * WELEM;
  ushort* ol = WL + (size_t)z * WELEM;
  size_t i = ((size_t)blockIdx.x * 256 + threadIdx.x) * 4;
  float4 v = *reinterpret_cast<const float4*>(&src[i]);
  ushort4 hv, lv;
  hv.x = f2bh(v.x); lv.x = f2bh(v.x - bh2f(hv.x));
  hv.y = f2bh(v.y); lv.y = f2bh(v.y - bh2f(hv.y));
  hv.z = f2bh(v.z); lv.z = f2bh(v.z - bh2f(hv.z));
  hv.w = f2bh(v.w); lv.w = f2bh(v.w - bh2f(hv.w));
  *reinterpret_cast<ushort4*>(&oh[i]) = hv;
  *reinterpret_cast<ushort4*>(&ol[i]) = lv;
}

// ============================================================================
// bf16x3 MFMA GEMM core: C[128x64] += A(hi+lo) * W(hi+lo)^T  (unchanged)
// ============================================================================
__device__ __forceinline__ void gemm_bf3_core(
    const ushort* __restrict__ Ah, const ushort* __restrict__ Al,
    const ushort* __restrict__ Wh, const ushort* __restrict__ Wl,
    int rowbase, int colbase, f32x4 (&acc)[4][2]) {
  __shared__ __align__(16) ushort AhS[128 * 64];
  __shared__ __align__(16) ushort AlS[128 * 64];
  __shared__ __align__(16) ushort WhS[64 * 64];
  __shared__ __align__(16) ushort WlS[64 * 64];
  char* AhB = (char*)AhS; char* AlB = (char*)AlS;
  char* WhB = (char*)WhS; char* WlB = (char*)WlS;

  const int tid  = threadIdx.x;
  const int lane = tid & 63;
  const int w    = tid >> 6;
  const int wm   = w >> 1;
  const int wn   = w & 1;
  const int lr   = lane & 15;
  const int lk   = lane >> 4;

  const int r0 = tid >> 3;          // 0..31
  const int cb = (tid & 7) * 16;    // byte col in LDS row
  const int ce = (tid & 7) * 8;     // element col
  const int sA0 = SWZ(r0, cb);
  const int sA1 = SWZ(r0 + 32, cb);
  const int sA2 = SWZ(r0 + 64, cb);
  const int sA3 = SWZ(r0 + 96, cb);

#pragma unroll
  for (int mt = 0; mt < 4; ++mt)
#pragma unroll
    for (int nt = 0; nt < 2; ++nt) acc[mt][nt] = {0.f, 0.f, 0.f, 0.f};

  float4 gA0h, gA1h, gA2h, gA3h, gA0l, gA1l, gA2l, gA3l;
  float4 gW0h, gW1h, gW0l, gW1l;

#define GEMM_ISSUE(k0_)                                                     \
  {                                                                         \
    size_t oA = (size_t)(rowbase + r0) * D_MODEL + (k0_) + ce;              \
    const size_t st = 32 * (size_t)D_MODEL;                                 \
    gA0h = *reinterpret_cast<const float4*>(Ah + oA);                       \
    gA1h = *reinterpret_cast<const float4*>(Ah + oA + st);                  \
    gA2h = *reinterpret_cast<const float4*>(Ah + oA + 2 * st);              \
    gA3h = *reinterpret_cast<const float4*>(Ah + oA + 3 * st);              \
    gA0l = *reinterpret_cast<const float4*>(Al + oA);                       \
    gA1l = *reinterpret_cast<const float4*>(Al + oA + st);                  \
    gA2l = *reinterpret_cast<const float4*>(Al + oA + 2 * st);              \
    gA3l = *reinterpret_cast<const float4*>(Al + oA + 3 * st);              \
    size_t oW = (size_t)(colbase + r0) * D_MODEL + (k0_) + ce;              \
    gW0h = *reinterpret_cast<const float4*>(Wh + oW);                       \
    gW1h = *reinterpret_cast<const float4*>(Wh + oW + st);                  \
    gW0l = *reinterpret_cast<const float4*>(Wl + oW);                       \
    gW1l = *reinterpret_cast<const float4*>(Wl + oW + st);                  \
  }

  GEMM_ISSUE(0);
  for (int ks = 0; ks < D_MODEL / 64; ++ks) {
    __syncthreads();  // prior compute done reading LDS
    *reinterpret_cast<float4*>(AhB + sA0) = gA0h;
    *reinterpret_cast<float4*>(AhB + sA1) = gA1h;
    *reinterpret_cast<float4*>(AhB + sA2) = gA2h;
    *reinterpret_cast<float4*>(AhB + sA3) = gA3h;
    *reinterpret_cast<float4*>(AlB + sA0) = gA0l;
    *reinterpret_cast<float4*>(AlB + sA1) = gA1l;
    *reinterpret_cast<float4*>(AlB + sA2) = gA2l;
    *reinterpret_cast<float4*>(AlB + sA3) = gA3l;
    *reinterpret_cast<float4*>(WhB + sA0) = gW0h;
    *reinterpret_cast<float4*>(WhB + sA1) = gW1h;
    *reinterpret_cast<float4*>(WlB + sA0) = gW0l;
    *reinterpret_cast<float4*>(WlB + sA1) = gW1l;
    __syncthreads();
    if (ks < D_MODEL / 64 - 1) GEMM_ISSUE((ks + 1) * 64);  // hide under MFMA

#pragma unroll
    for (int kc = 0; kc < 2; ++kc) {
      short8 ah[4], al[4], bh[2], bl[2];
#pragma unroll
      for (int mt = 0; mt < 4; ++mt) {
        int o = SWZ(wm * 64 + mt * 16 + lr, kc * 64 + lk * 16);
        ah[mt] = *reinterpret_cast<const short8*>(AhB + o);
        al[mt] = *reinterpret_cast<const short8*>(AlB + o);
      }
#pragma unroll
      for (int nt = 0; nt < 2; ++nt) {
        int o = SWZ(wn * 32 + nt * 16 + lr, kc * 64 + lk * 16);
        bh[nt] = *reinterpret_cast<const short8*>(WhB + o);
        bl[nt] = *reinterpret_cast<const short8*>(WlB + o);
      }
#pragma unroll
      for (int mt = 0; mt < 4; ++mt)
#pragma unroll
        for (int nt = 0; nt < 2; ++nt) {
          acc[mt][nt] = __builtin_amdgcn_mfma_f32_16x16x32_bf16(
              ah[mt], bh[nt], acc[mt][nt], 0, 0, 0);
          acc[mt][nt] = __builtin_amdgcn_mfma_f32_16x16x32_bf16(
              al[mt], bh[nt], acc[mt][nt], 0, 0, 0);
          acc[mt][nt] = __builtin_amdgcn_mfma_f32_16x16x32_bf16(
              ah[mt], bl[nt], acc[mt][nt], 0, 0, 0);
        }
    }
  }
#undef GEMM_ISSUE
}

// QKV projections: grid (12, 32, 3); z: 0=Q(scale (1/8)/ln2), 1=K, 2=V.
__global__ __launch_bounds__(256)
void gemm_qkv_bf3(const ushort* __restrict__ xh, const ushort* __restrict__ xl,
                  const ushort* __restrict__ WH, const ushort* __restrict__ WL,
                  ushort* __restrict__ QKV) {
  const int z = blockIdx.z;
  const ushort* Wh = WH + (size_t)z * WELEM;
  const ushort* Wl = WL + (size_t)z * WELEM;
  ushort* oh = QKV + (size_t)z * (2 * NELEM);
  ushort* ol = oh + NELEM;
  const float scale = (z == 0) ? 0.125f * 1.44269504089f : 1.0f;
  const int rowbase = blockIdx.y * 128;
  const int colbase = blockIdx.x * 64;

  f32x4 acc[4][2];
  gemm_bf3_core(xh, xl, Wh, Wl, rowbase, colbase, acc);

  const int lane = threadIdx.x & 63, w = threadIdx.x >> 6;
  const int wm = w >> 1, wn = w & 1, lr = lane & 15, lk = lane >> 4;
#pragma unroll
  for (int mt = 0; mt < 4; ++mt)
#pragma unroll
    for (int nt = 0; nt < 2; ++nt)
#pragma unroll
      for (int j = 0; j < 4; ++j) {
        int rg = rowbase + wm * 64 + mt * 16 + lk * 4 + j;
        int cg = colbase + wn * 32 + nt * 16 + lr;
        float v = acc[mt][nt][j] * scale;
        ushort hh = f2bh(v);
        oh[(size_t)rg * D_MODEL + cg] = hh;
        ol[(size_t)rg * D_MODEL + cg] = f2bh(v - bh2f(hh));
      }
}

// Output projection: fp32 out + bias.
__global__ __launch_bounds__(256)
void gemm_out_bf3(const ushort* __restrict__ ch, const ushort* __restrict__ cl,
                  const ushort* __restrict__ woh, const ushort* __restrict__ wol,
                  const float* __restrict__ bo, float* __restrict__ out) {
  const int rowbase = blockIdx.y * 128;
  const int colbase = blockIdx.x * 64;
  f32x4 acc[4][2];
  gemm_bf3_core(ch, cl, woh, wol, rowbase, colbase, acc);

  const int lane = threadIdx.x & 63, w = threadIdx.x >> 6;
  const int wm = w >> 1, wn = w & 1, lr = lane & 15, lk = lane >> 4;
#pragma unroll
  for (int nt = 0; nt < 2; ++nt) {
    int cg = colbase + wn * 32 + nt * 16 + lr;
    float bb = bo[cg];
#pragma unroll
    for (int mt = 0; mt < 4; ++mt)
#pragma unroll
      for (int j = 0; j < 4; ++j) {
        int rg = rowbase + wm * 64 + mt * 16 + lk * 4 + j;
        out[(size_t)rg * D_MODEL + cg] = acc[mt][nt][j] + bb;
      }
  }
}

// ============================================================================
// V transpose: row-major hi/lo planes -> [h][d][s] hi/lo planes. (unchanged)
// ============================================================================
__global__ __launch_bounds__(256)
void convert_vt(const ushort* __restrict__ Vrh, const ushort* __restrict__ Vrl,
                ushort* __restrict__ Vth, ushort* __restrict__ Vtl) {
  __shared__ ushort th[64][68];
  __shared__ ushort tl[64][68];
  const int tid = threadIdx.x;
  const int s0  = blockIdx.x * 64;
  const int h   = blockIdx.y;
#pragma unroll
  for (int it = 0; it < 4; ++it) {
    int id = tid + it * 256;
    int s  = id >> 4;
    int c4 = (id & 15) * 4;
    size_t g = (size_t)(s0 + s) * D_MODEL + h * H_DIM + c4;
    ushort4 vh = *reinterpret_cast<const ushort4*>(&Vrh[g]);
    ushort4 vl = *reinterpret_cast<const ushort4*>(&Vrl[g]);
    th[c4 + 0][s] = vh.x; th[c4 + 1][s] = vh.y;
    th[c4 + 2][s] = vh.z; th[c4 + 3][s] = vh.w;
    tl[c4 + 0][s] = vl.x; tl[c4 + 1][s] = vl.y;
    tl[c4 + 2][s] = vl.z; tl[c4 + 3][s] = vl.w;
  }
  __syncthreads();
#pragma unroll
  for (int it = 0; it < 4; ++it) {
    int id = tid + it * 256;
    int d  = id >> 4;
    int s4 = (id & 15) * 4;
    ushort4 oh, ol;
    oh.x = th[d][s4 + 0]; oh.y = th[d][s4 + 1];
    oh.z = th[d][s4 + 2]; oh.w = th[d][s4 + 3];
    ol.x = tl[d][s4 + 0]; ol.y = tl[d][s4 + 1];
    ol.z = tl[d][s4 + 2]; ol.w = tl[d][s4 + 3];
    size_t o = (size_t)(h * H_DIM + d) * S_LEN + s0 + s4;
    *reinterpret_cast<ushort4*>(&Vth[o]) = oh;
    *reinterpret_cast<ushort4*>(&Vtl[o]) = ol;
  }
}

// ============================================================================
// Flash attention fwd (causal), SWAPPED QK^T (S^T = mfma(K,Q)) so each lane
// owns one q-row -> in-register softmax + in-register P (cvt_pk + shfl
// gather feeds PV's A-operand directly; no P LDS). bf16x3 QK^T, bf16x2 PV.
// Schedule identical to R9 (1-D grid, head fast-varying, heavy-first).
// LDS = 32768 B (K/V hi/lo only).
// ============================================================================
__global__ __launch_bounds__(256)
void attn_mfma(const ushort* __restrict__ Qh_g, const ushort* __restrict__ Ql_g,
               const ushort* __restrict__ Kh_g, const ushort* __restrict__ Kl_g,
               const ushort* __restrict__ Vh_g, const ushort* __restrict__ Vl_g,
               ushort* __restrict__ CTXh, ushort* __restrict__ CTXl,
               float* __restrict__ O_part, float* __restrict__ m_part,
               float* __restrict__ l_part) {
  const int bxl = blockIdx.x;        // 0..1919
  const int h   = bxl % N_HEAD;      // fast-varying: heads interleave
  const int i   = bxl / N_HEAD;      // 0..159, global heavy-first order
  int qb, c = 0, nch = 1, slot = 0, partial = 0;
  if (i < 8) {
    qb = 15 - i;                     // long direct blocks first (16..9 tiles)
  } else if (i < 152) {
    int j = i - 8;
    if (j < 64)       { qb = 63 - (j >> 2);        c = j & 3;        nch = 4; }
    else if (j < 112) { int off = j - 64;  qb = 47 - off / 3; c = off % 3; nch = 3; }
    else              { int off = j - 112; qb = 31 - off / 2; c = off & 1; nch = 2; }
    partial = 1;
    slot = h * 144 + j;
  } else {
    qb = 159 - i;                    // shortest directs last (8..1 tiles)
  }
  const int kt0 = c * (qb + 1) / nch;
  const int kt1 = (c + 1) * (qb + 1) / nch;

  __shared__ __align__(16) ushort Kh_s[64 * 64];
  __shared__ __align__(16) ushort Kl_s[64 * 64];
  __shared__ __align__(16) ushort Vh_s[64 * 64];
  __shared__ __align__(16) ushort Vl_s[64 * 64];

  char* KhB = (char*)Kh_s;
  char* KlB = (char*)Kl_s;
  char* VhB = (char*)Vh_s;
  char* VlB = (char*)Vl_s;

  const int tid  = threadIdx.x;
  const int lane = tid & 63;
  const int w    = tid >> 6;
  const int lr   = lane & 15;   // q-row within wave tile (after swap)
  const int lk   = lane >> 4;   // k-group
  const float NEG = -1e30f;

  const int r0 = tid >> 3;          // 0..31
  const int cb = (tid & 7) * 16;
  const int ce = (tid & 7) * 8;
  const int swA = SWZ(r0, cb);
  const int swB = SWZ(r0 + 32, cb);

  // ---- Prologue: stage Q tile through K buffers, hoist B-frags to regs ----
  {
    size_t g0 = (size_t)(qb * 64 + r0) * D_MODEL + h * H_DIM + ce;
    size_t g1 = g0 + 32 * (size_t)D_MODEL;
    *reinterpret_cast<float4*>(KhB + swA) =
        *reinterpret_cast<const float4*>(Qh_g + g0);
    *reinterpret_cast<float4*>(KhB + swB) =
        *reinterpret_cast<const float4*>(Qh_g + g1);
    *reinterpret_cast<float4*>(KlB + swA) =
        *reinterpret_cast<const float4*>(Ql_g + g0);
    *reinterpret_cast<float4*>(KlB + swB) =
        *reinterpret_cast<const float4*>(Ql_g + g1);
  }
  __syncthreads();
  short8 aqh[2], aql[2];
#pragma unroll
  for (int kc = 0; kc < 2; ++kc) {
    int ao = SWZ(w * 16 + lr, kc * 64 + lk * 16);
    aqh[kc] = *reinterpret_cast<const short8*>(KhB + ao);
    aql[kc] = *reinterpret_cast<const short8*>(KlB + ao);
  }

  f32x4 o[4];
  float m = NEG, l = 0.f;  // per-lane: q-row = w*16+lr
#pragma unroll
  for (int t = 0; t < 4; ++t) o[t] = {0.f, 0.f, 0.f, 0.f};

  // T14 prefetch: named registers + incremental offsets.
  float4 gkh0, gkh1, gkl0, gkl1, gvh0, gvh1, gvl0, gvl1;
  size_t gk0 = (size_t)(kt0 * 64 + r0) * D_MODEL + h * H_DIM + ce;
  size_t gk1 = gk0 + 32 * (size_t)D_MODEL;
  size_t gv0 = (size_t)(h * H_DIM + r0) * S_LEN + kt0 * 64 + ce;
  size_t gv1 = gv0 + 32 * (size_t)S_LEN;

#define ATTN_ISSUE()                                                        \
  {                                                                         \
    gkh0 = *reinterpret_cast<const float4*>(Kh_g + gk0);                    \
    gkh1 = *reinterpret_cast<const float4*>(Kh_g + gk1);                    \
    gkl0 = *reinterpret_cast<const float4*>(Kl_g + gk0);                    \
    gkl1 = *reinterpret_cast<const float4*>(Kl_g + gk1);                    \
    gvh0 = *reinterpret_cast<const float4*>(Vh_g + gv0);                    \
    gvh1 = *reinterpret_cast<const float4*>(Vh_g + gv1);                    \
    gvl0 = *reinterpret_cast<const float4*>(Vl_g + gv0);                    \
    gvl1 = *reinterpret_cast<const float4*>(Vl_g + gv1);                    \
    gk0 += 64 * (size_t)D_MODEL; gk1 += 64 * (size_t)D_MODEL;               \
    gv0 += 64; gv1 += 64;                                                   \
  }

  ATTN_ISSUE();

  for (int kt = kt0; kt < kt1; ++kt) {
    __syncthreads();  // prior tile's LDS reads done (covers Q-frag reads too)
    *reinterpret_cast<float4*>(KhB + swA) = gkh0;
    *reinterpret_cast<float4*>(KhB + swB) = gkh1;
    *reinterpret_cast<float4*>(KlB + swA) = gkl0;
    *reinterpret_cast<float4*>(KlB + swB) = gkl1;
    *reinterpret_cast<float4*>(VhB + swA) = gvh0;
    *reinterpret_cast<float4*>(VhB + swB) = gvh1;
    *reinterpret_cast<float4*>(VlB + swA) = gvl0;
    *reinterpret_cast<float4*>(VlB + swB) = gvl1;
    __syncthreads();
    if (kt + 1 < kt1) ATTN_ISSUE();  // in flight during compute

    // ---- S^T = K Q^T (bf16x3; swapped operands). sacc[t][r] =
    //      S[k = kt*64 + t*16 + lk*4 + r][q = w*16 + lr] ----
    f32x4 sacc[4];
#pragma unroll
    for (int t = 0; t < 4; ++t) sacc[t] = {0.f, 0.f, 0.f, 0.f};
#pragma unroll
    for (int kc = 0; kc < 2; ++kc) {
#pragma unroll
      for (int t = 0; t < 4; ++t) {
        int bo = SWZ(t * 16 + lr, kc * 64 + lk * 16);
        short8 kh = *reinterpret_cast<const short8*>(KhB + bo);
        short8 kl = *reinterpret_cast<const short8*>(KlB + bo);
        sacc[t] = __builtin_amdgcn_mfma_f32_16x16x32_bf16(kh, aqh[kc], sacc[t], 0, 0, 0);
        sacc[t] = __builtin_amdgcn_mfma_f32_16x16x32_bf16(kl, aqh[kc], sacc[t], 0, 0, 0);
        sacc[t] = __builtin_amdgcn_mfma_f32_16x16x32_bf16(kh, aql[kc], sacc[t], 0, 0, 0);
      }
    }

    // ---- causal mask on the diagonal tile (k_loc > q_loc) ----
    if (kt == qb) {
      int qloc = w * 16 + lr;
#pragma unroll
      for (int t = 0; t < 4; ++t)
#pragma unroll
        for (int r = 0; r < 4; ++r)
          if (t * 16 + lk * 4 + r > qloc) sacc[t][r] = NEG;
    }

    // ---- online softmax, exp2 domain, fully per-lane (q = w*16+lr) ----
    float mx = fmaxf(fmaxf(fmaxf(sacc[0][0], sacc[0][1]),
                           fmaxf(sacc[0][2], sacc[0][3])),
                     fmaxf(fmaxf(sacc[1][0], sacc[1][1]),
                           fmaxf(sacc[1][2], sacc[1][3])));
    mx = fmaxf(mx, fmaxf(fmaxf(fmaxf(sacc[2][0], sacc[2][1]),
                               fmaxf(sacc[2][2], sacc[2][3])),
                         fmaxf(fmaxf(sacc[3][0], sacc[3][1]),
                               fmaxf(sacc[3][2], sacc[3][3]))));
    mx = fmaxf(mx, __shfl_xor(mx, 16));
    mx = fmaxf(mx, __shfl_xor(mx, 32));
    if (__any(mx > m)) {  // wave-uniform; alpha==1 for unchanged rows (exact)
      float mnew  = fmaxf(m, mx);
      float alpha = exp2f(m - mnew);
      m = mnew;
      l *= alpha;
      // Broadcast alpha to O-rows (O row q = lk*4+r; alpha lives at lr == q).
      int bsrc = (lane & 48) | (((lane >> 4) & 3) << 2);
#pragma unroll
      for (int r = 0; r < 4; ++r) {
        float ar = __shfl(alpha, bsrc + r);
#pragma unroll
        for (int t = 0; t < 4; ++t) o[t][r] *= ar;
      }
    }
    // P = exp2(S - m), packed to bf16 pairs in-register.
    unsigned u0[4], u1[4];
#pragma unroll
    for (int t = 0; t < 4; ++t) {
      float p0 = exp2f(sacc[t][0] - m);
      float p1 = exp2f(sacc[t][1] - m);
      float p2 = exp2f(sacc[t][2] - m);
      float p3 = exp2f(sacc[t][3] - m);
      l += (p0 + p1) + (p2 + p3);
      u0[t] = cvtpk_bf16(p0, p1);
      u1[t] = cvtpk_bf16(p2, p3);
    }

    // ---- O += P V: gather P A-frags via shfl, no LDS round-trip ----
    {
      int srcA = ((2 * (lk & 1)) << 4) | lr;
      int srcB = srcA + 16;
      int hi   = (lk >> 1) & 1;
#pragma unroll
      for (int kc = 0; kc < 2; ++kc) {
        unsigned aA0 = __shfl(u0[2 * kc], srcA), bA0 = __shfl(u0[2 * kc + 1], srcA);
        unsigned aA1 = __shfl(u1[2 * kc], srcA), bA1 = __shfl(u1[2 * kc + 1], srcA);
        unsigned aB0 = __shfl(u0[2 * kc], srcB), bB0 = __shfl(u0[2 * kc + 1], srcB);
        unsigned aB1 = __shfl(u1[2 * kc], srcB), bB1 = __shfl(u1[2 * kc + 1], srcB);
        i32x4 tv;
        tv[0] = (int)(hi ? bA0 : aA0);
        tv[1] = (int)(hi ? bA1 : aA1);
        tv[2] = (int)(hi ? bB0 : aB0);
        tv[3] = (int)(hi ? bB1 : aB1);
        short8 pa = __builtin_bit_cast(short8, tv);
#pragma unroll
        for (int t = 0; t < 4; ++t) {
          int bo = SWZ(t * 16 + lr, kc * 64 + lk * 16);
          short8 vh = *reinterpret_cast<const short8*>(VhB + bo);
          short8 vl = *reinterpret_cast<const short8*>(VlB + bo);
          o[t] = __builtin_amdgcn_mfma_f32_16x16x32_bf16(pa, vh, o[t], 0, 0, 0);
          o[t] = __builtin_amdgcn_mfma_f32_16x16x32_bf16(pa, vl, o[t], 0, 0, 0);
        }
      }
    }
  }
#undef ATTN_ISSUE

  // ---- final l reduction across the 4 k-groups (disjoint k subsets) ----
  l += __shfl_xor(l, 16);
  l += __shfl_xor(l, 32);

  if (!partial) {
    // ---- direct epilogue: normalize, store ctx as hi/lo bf16 planes ----
    float rl = 1.f / l;
    int bsrc = (lane & 48) | (((lane >> 4) & 3) << 2);
#pragma unroll
    for (int r = 0; r < 4; ++r) {
      float invr = __shfl(rl, bsrc + r);
#pragma unroll
      for (int t = 0; t < 4; ++t) {
        size_t idx = (size_t)(qb * 64 + w * 16 + lk * 4 + r) * D_MODEL +
                     h * H_DIM + t * 16 + lr;
        float v = o[t][r] * invr;
        ushort hh = f2bh(v);
        CTXh[idx] = hh;
        CTXl[idx] = f2bh(v - bh2f(hh));
      }
    }
  } else {
    // ---- partial epilogue: unnormalized fp32 O + m + l (m in log2) ----
    float* Ob = O_part + (size_t)slot * 4096;
#pragma unroll
    for (int t = 0; t < 4; ++t)
#pragma unroll
      for (int r = 0; r < 4; ++r)
        Ob[(w * 16 + lk * 4 + r) * 64 + t * 16 + lr] = o[t][r];
    if ((lane >> 4) == 0) {  // lanes 0..15 hold q-rows w*16 + lr
      m_part[slot * 64 + w * 16 + lr] = m;
      l_part[slot * 64 + w * 16 + lr] = l;
    }
  }
}

// ============================================================================
// Combine 2-4 partials per (h, qb>=16). (unchanged from R9)
// ============================================================================
__global__ __launch_bounds__(256)
void attn_combine(const float* __restrict__ O_part,
                  const float* __restrict__ m_part,
                  const float* __restrict__ l_part,
                  ushort* __restrict__ CTXh, ushort* __restrict__ CTXl) {
  const int qb  = 16 + blockIdx.x;  // 16..63
  const int h   = blockIdx.y;
  const int tid = threadIdx.x;
  const int row = tid >> 2;        // 0..63
  const int d0  = (tid & 3) * 16;  // 0,16,32,48
  int nch, sbl;
  if (qb >= 48)      { nch = 4; sbl = (63 - qb) * 4; }
  else if (qb >= 32) { nch = 3; sbl = 64 + (47 - qb) * 3; }
  else               { nch = 2; sbl = 112 + (31 - qb) * 2; }
  const int sb = h * 144 + sbl;
  const int s2 = (nch >= 3) ? sb + 2 : sb;
  const int s3 = (nch >= 4) ? sb + 3 : sb;

  float m0 = m_part[(sb + 0) * 64 + row];
  float m1 = m_part[(sb + 1) * 64 + row];
  float m2 = (nch >= 3) ? m_part[s2 * 64 + row] : -1e30f;
  float m3 = (nch >= 4) ? m_part[s3 * 64 + row] : -1e30f;
  float l0 = l_part[(sb + 0) * 64 + row];
  float l1 = l_part[(sb + 1) * 64 + row];
  float l2 = (nch >= 3) ? l_part[s2 * 64 + row] : 0.f;
  float l3 = (nch >= 4) ? l_part[s3 * 64 + row] : 0.f;
  float M  = fmaxf(fmaxf(m0, m1), fmaxf(m2, m3));
  float a0 = exp2f(m0 - M);
  float a1 = exp2f(m1 - M);
  float a2 = (nch >= 3) ? exp2f(m2 - M) : 0.f;
  float a3 = (nch >= 4) ? exp2f(m3 - M) : 0.f;
  float inv = 1.0f / (l0 * a0 + l1 * a1 + l2 * a2 + l3 * a3);

  const float* p0 = O_part + (size_t)(sb + 0) * 4096 + row * 64 + d0;
  const float* p1 = O_part + (size_t)(sb + 1) * 4096 + row * 64 + d0;
  const float* p2 = O_part + (size_t)s2 * 4096 + row * 64 + d0;
  const float* p3 = O_part + (size_t)s3 * 4096 + row * 64 + d0;
  size_t ob = (size_t)(qb * 64 + row) * D_MODEL + h * H_DIM + d0;
#pragma unroll
  for (int j = 0; j < 16; j += 4) {
    float4 x0 = *reinterpret_cast<const float4*>(p0 + j);
    float4 x1 = *reinterpret_cast<const float4*>(p1 + j);
    float4 x2 = *reinterpret_cast<const float4*>(p2 + j);
    float4 x3 = *reinterpret_cast<const float4*>(p3 + j);
    float4 v;
    v.x = (x0.x * a0 + x1.x * a1 + x2.x * a2 + x3.x * a3) * inv;
    v.y = (x0.y * a0 + x1.y * a1 + x2.y * a2 + x3.y * a3) * inv;
    v.z = (x0.z * a0 + x1.z * a1 + x2.z * a2 + x3.z * a3) * inv;
    v.w = (x0.w * a0 + x1.w * a1 + x2.w * a2 + x3.w * a3) * inv;
    ushort4 hv, lv;
    hv.x = f2bh(v.x); lv.x = f2bh(v.x - bh2f(hv.x));
    hv.y = f2bh(v.y); lv.y = f2bh(v.y - bh2f(hv.y));
    hv.z = f2bh(v.z); lv.z = f2bh(v.z - bh2f(hv.z));
    hv.w = f2bh(v.w); lv.w = f2bh(v.w - bh2f(hv.w));
    *reinterpret_cast<ushort4*>(&CTXh[ob + j]) = hv;
    *reinterpret_cast<ushort4*>(&CTXl[ob + j]) = lv;
  }
}

// ============================================================================
extern "C" void kernel_launch(void* const* d_in, const int* in_sizes, int n_in,
                              void* d_out, int out_size, void* d_ws,
                              size_t ws_size, hipStream_t stream) {
  // setup_inputs order: x, w_k, w_q, w_v, w_o, b_o
  const float* x  = (const float*)d_in[0];
  const float* wk = (const float*)d_in[1];
  const float* wq = (const float*)d_in[2];
  const float* wv = (const float*)d_in[3];
  const float* wo = (const float*)d_in[4];
  const float* bo = (const float*)d_in[5];
  float* out = (float*)d_out;

  // Workspace layout (ushort elements). CTX aliases Vr (dead after
  // convert_vt). Total ~101 MiB (same as R9).
  ushort* xh   = (ushort*)d_ws;
  ushort* xl   = xh + NELEM;
  ushort* WH   = xl + NELEM;          // 4 planes: q,k,v,o
  ushort* WL   = WH + 4 * (size_t)WELEM;
  ushort* QKV  = WL + 4 * (size_t)WELEM;  // [Qh][Ql][Kh][Kl][Vrh][Vrl]
  ushort* Qh   = QKV;
  ushort* Ql   = Qh + NELEM;
  ushort* Kh   = Ql + NELEM;
  ushort* Kl   = Kh + NELEM;
  ushort* Vrh  = Kl + NELEM;
  ushort* Vrl  = Vrh + NELEM;
  ushort* Vth  = Vrl + NELEM;
  ushort* Vtl  = Vth + NELEM;
  ushort* CTXh = Vrh;  // alias: Vr dead after convert_vt
  ushort* CTXl = Vrl;
  float* O_part = (float*)(Vtl + NELEM);        // 1728 slots x 64 x 64 fp32
  float* m_part = O_part + 1728 * (size_t)4096; // 1728 x 64
  float* l_part = m_part + 1728 * 64;

  dim3 blk(256);
  convert_x<<<dim3(NELEM / 4 / 256), blk, 0, stream>>>(x, xh, xl);
  convert_w<<<dim3(WELEM / 4 / 256, 1, 4), blk, 0, stream>>>(wq, wk, wv, wo,
                                                             WH, WL);
  gemm_qkv_bf3<<<dim3(D_MODEL / 64, S_LEN / 128, 3), blk, 0, stream>>>(
      xh, xl, WH, WL, QKV);
  convert_vt<<<dim3(S_LEN / 64, N_HEAD), blk, 0, stream>>>(Vrh, Vrl, Vth, Vtl);
  attn_mfma<<<dim3(160 * N_HEAD), blk, 0, stream>>>(
      Qh, Ql, Kh, Kl, Vth, Vtl, CTXh, CTXl, O_part, m_part, l_part);
  attn_combine<<<dim3(48, N_HEAD), blk, 0, stream>>>(O_part, m_part, l_part,
                                                     CTXh, CTXl);
  gemm_out_bf3<<<dim3(D_MODEL / 64, S_LEN / 128, 1), blk, 0, stream>>>(
      CTXh, CTXl, WH + 3 * (size_t)WELEM, WL + 3 * (size_t)WELEM, bo, out);
}